// Round 11
// baseline (192.289 us; speedup 1.0000x reference)
//
#include <hip/hip_runtime.h>

typedef short bf16x8 __attribute__((ext_vector_type(8)));
typedef float f32x4 __attribute__((ext_vector_type(4)));
typedef float f32x16 __attribute__((ext_vector_type(16)));
typedef float float4v __attribute__((ext_vector_type(4)));
typedef short short4v __attribute__((ext_vector_type(4)));
typedef unsigned uint2v __attribute__((ext_vector_type(2)));
typedef unsigned uint4v __attribute__((ext_vector_type(4)));

#define B_ 4
#define S_ 2048
#define E_ 1024
#define H_ 16
#define D_ 64
#define M_ (B_*S_)      // 8192
#define N1_ (3*E_)      // 3072

__device__ inline short f2bs(float f) {
    unsigned u = __builtin_bit_cast(unsigned, f);
    unsigned r = u + 0x7fffu + ((u >> 16) & 1u);
    return (short)(r >> 16);
}
__device__ inline float exp2a(float x) {
    float r; asm("v_exp_f32 %0, %1" : "=v"(r) : "v"(x)); return r;
}
__device__ inline unsigned cvtpk(float a, float b) {
    unsigned r; asm("v_cvt_pk_bf16_f32 %0, %1, %2" : "=v"(r) : "v"(a), "v"(b)); return r;
}

__device__ inline const __attribute__((address_space(1))) void* gas(const void* p) {
    return (const __attribute__((address_space(1))) void*)p;
}
__device__ inline __attribute__((address_space(3))) void* las(void* p) {
    return (__attribute__((address_space(3))) void*)p;
}

// ---------------- elementwise fp32 -> bf16 ----------------
__global__ void convert_f32_bf16(const float* __restrict__ in, short* __restrict__ out, int n) {
    int tid = blockIdx.x * blockDim.x + threadIdx.x;
    int stride = gridDim.x * blockDim.x;
    for (int i = tid * 4; i < n; i += stride * 4) {
        float4v v = *(const float4v*)&in[i];
        short4v o;
        o[0] = f2bs(v[0]); o[1] = f2bs(v[1]); o[2] = f2bs(v[2]); o[3] = f2bs(v[3]);
        *(short4v*)&out[i] = o;
    }
}

// ---------------- tiled transpose + convert ----------------
__global__ void transpose_convert(const float* __restrict__ in, short* __restrict__ out,
                                  int rows, int cols) {
    __shared__ float t[32][33];
    int bx = blockIdx.x * 32;
    int by = blockIdx.y * 32;
    int tx = threadIdx.x, ty = threadIdx.y;  // (32, 8)
#pragma unroll
    for (int i = 0; i < 4; ++i)
        t[ty + i * 8][tx] = in[(size_t)(by + ty + i * 8) * cols + bx + tx];
    __syncthreads();
#pragma unroll
    for (int i = 0; i < 4; ++i)
        out[(size_t)(bx + ty + i * 8) * rows + by + tx] = f2bs(t[tx][ty + i * 8]);
}

// ================= 256x128 8-phase GEMM (QKV), grid 768 = 3x256 exact =================
// 8 waves (2M x 4N): per-wave 128 rows x 32 cols. BK=64. 96KB LDS dbuf.
// Loads/K-tile: B 2, A-seg0 2, A-seg1 2. Schedule: P0 stage B | P1 stage A-s0 + VMW(4)
// | P2 stage A-s1 | P3 VMW(2).
#define MFMA8(Q) \
    _Pragma("unroll") for (int mf = 0; mf < 2; ++mf) \
    _Pragma("unroll") for (int nf = 0; nf < 2; ++nf) { \
        acc[(Q)*2+mf][nf] = __builtin_amdgcn_mfma_f32_16x16x32_bf16(af[mf][0], bfrag[nf][0], acc[(Q)*2+mf][nf], 0, 0, 0); \
        acc[(Q)*2+mf][nf] = __builtin_amdgcn_mfma_f32_16x16x32_bf16(af[mf][1], bfrag[nf][1], acc[(Q)*2+mf][nf], 0, 0, 0); \
    }

#define PHASE(Q, STAGE_STMT, WAITV) do { \
    bf16x8 af[2][2]; \
    _Pragma("unroll") for (int mf = 0; mf < 2; ++mf) \
    _Pragma("unroll") for (int ks = 0; ks < 2; ++ks) { \
        int r = (Q)*32 + mf*16 + li; \
        af[mf][ks] = *(const bf16x8*)(lA + r*128 + ((ks*64 + g*16) ^ ((r & 7) << 4))); \
    } \
    STAGE_STMT; \
    __builtin_amdgcn_s_barrier(); \
    asm volatile("s_waitcnt lgkmcnt(0)" ::: "memory"); \
    __builtin_amdgcn_sched_barrier(0); \
    __builtin_amdgcn_s_setprio(1); \
    MFMA8(Q); \
    __builtin_amdgcn_s_setprio(0); \
    WAITV; \
    __builtin_amdgcn_s_barrier(); \
} while (0)

#define VMW(n) asm volatile("s_waitcnt vmcnt(" #n ")" ::: "memory")
#define NOP_ ((void)0)

__global__ __launch_bounds__(512, 2) void gemm_qkv(
    const short* __restrict__ A, const short* __restrict__ Bt,
    const float* __restrict__ bias,
    short* __restrict__ Qb, short* __restrict__ Kb, short* __restrict__ Vt) {
    __shared__ __attribute__((aligned(16))) short ldsA[2][2][2][4096];  // [buf][half][seg][64x64]
    __shared__ __attribute__((aligned(16))) short ldsB[2][8192];        // [buf][128x64]
    const int tid = threadIdx.x;
    const int lane = tid & 63;
    const int wid = tid >> 6;
    const int li = lane & 15, g = lane >> 4;
    const int wr = wid >> 2, wc = wid & 3;
    const int Kdim = E_;       // 1024
    const int NT = Kdim >> 6;  // 16 K-tiles

    // bijective XCD swizzle: nwg=768, 768/8=96
    const int id = blockIdx.x;
    const int swz = (id & 7) * 96 + (id >> 3);
    const int bx = swz % 24, by = swz / 24;
    const int row0 = by * 256, col0 = bx * 128;

    // staging lane geometry: linear LDS dest, inverse-swizzled global src
    const int rstage = wid * 8 + (lane >> 3);                     // 0..63
    const int cstage = (((lane & 7) ^ ((lane >> 3) & 7)) << 4);

    auto stageA = [&](int buf, int kt, int seg) {
#pragma unroll
        for (int h = 0; h < 2; ++h) {
            const char* src = (const char*)A +
                ((size_t)(row0 + h * 128 + seg * 64 + rstage) * Kdim + kt * 64) * 2 + cstage;
            char* dst = (char*)&ldsA[buf][h][seg][0] + wid * 1024;
            __builtin_amdgcn_global_load_lds(gas(src), las(dst), 16, 0, 0);
        }
    };
    auto stageB = [&](int buf, int kt) {
#pragma unroll
        for (int i = 0; i < 2; ++i) {
            const char* src = (const char*)Bt +
                ((size_t)(col0 + i * 64 + rstage) * Kdim + kt * 64) * 2 + cstage;
            char* dst = (char*)&ldsB[buf][0] + i * 8192 + wid * 1024;
            __builtin_amdgcn_global_load_lds(gas(src), las(dst), 16, 0, 0);
        }
    };

    f32x4 acc[8][2];
#pragma unroll
    for (int m = 0; m < 8; ++m)
#pragma unroll
        for (int n = 0; n < 2; ++n) acc[m][n] = (f32x4){0.f, 0.f, 0.f, 0.f};

    // prologue: tile 0 -> buf 0, full drain (once)
    stageB(0, 0);
    stageA(0, 0, 0);
    stageA(0, 0, 1);
    asm volatile("s_waitcnt vmcnt(0)" ::: "memory");
    __syncthreads();

    for (int t = 0; t < NT; ++t) {
        const int cur = t & 1;
        const int nb = cur ^ 1;
        const int tn = t + 1;
        const bool st = (tn < NT);
        const char* lA = (const char*)&ldsA[cur][wr][0][0];
        const char* lB = (const char*)&ldsB[cur][0];

        bf16x8 bfrag[2][2];
#pragma unroll
        for (int nf = 0; nf < 2; ++nf)
#pragma unroll
            for (int ks = 0; ks < 2; ++ks) {
                int r = wc * 32 + nf * 16 + li;
                bfrag[nf][ks] = *(const bf16x8*)(lB + r * 128 + ((ks * 64 + g * 16) ^ ((r & 7) << 4)));
            }
        if (st) {
            PHASE(0, stageB(nb, tn), NOP_);
            PHASE(1, stageA(nb, tn, 0), VMW(4));
            PHASE(2, stageA(nb, tn, 1), NOP_);
            PHASE(3, NOP_, VMW(2));
        } else {
            PHASE(0, NOP_, NOP_);
            PHASE(1, NOP_, VMW(0));
            PHASE(2, NOP_, NOP_);
            PHASE(3, NOP_, NOP_);
        }
    }

    // ---- epilogue (C layout: col = lane&15, row = (lane>>4)*4 + j) ----
    if (col0 < 2048) {
        short* Dst = (col0 < 1024) ? Qb : Kb;
#pragma unroll
        for (int nf = 0; nf < 2; ++nf) {
            int ncolg = col0 + wc * 32 + nf * 16 + li;
            float bv = bias[ncolg];
            int ncol = ncolg & 1023;
#pragma unroll
            for (int mi = 0; mi < 8; ++mi) {
                int rbase = row0 + wr * 128 + mi * 16 + 4 * g;
#pragma unroll
                for (int j = 0; j < 4; ++j)
                    Dst[(size_t)(rbase + j) * E_ + ncol] = f2bs(acc[mi][nf][j] + bv);
            }
        }
    } else {
#pragma unroll
        for (int nf = 0; nf < 2; ++nf) {
            int ncolg = col0 + wc * 32 + nf * 16 + li;
            float bv = bias[ncolg];
            int rem = ncolg & 1023;
            int h = rem >> 6, d = rem & 63;
#pragma unroll
            for (int mi = 0; mi < 8; ++mi) {
                int s0 = row0 + wr * 128 + mi * 16 + 4 * g;
                int bb2 = s0 >> 11;
                int ss = s0 & 2047;
                uint2v p;
                p[0] = cvtpk(acc[mi][nf][0] + bv, acc[mi][nf][1] + bv);
                p[1] = cvtpk(acc[mi][nf][2] + bv, acc[mi][nf][3] + bv);
                *(uint2v*)&Vt[((size_t)(bb2 * H_ + h) * D_ + d) * S_ + ss] = p;
            }
        }
    }
}

// ---------------- bf16 GEMM, 128x128 tile (out-proj) ----------------
__global__ __launch_bounds__(256, 2) void gemm_bt_out(
    const short* __restrict__ A, const short* __restrict__ Bt,
    const float* __restrict__ bias, float* __restrict__ Cf,
    int Kdim, int Ndim) {
    __shared__ __attribute__((aligned(16))) short As[128 * 32];
    __shared__ __attribute__((aligned(16))) short Bs[128 * 32];
    const int lane = threadIdx.x & 63;
    const int wv = threadIdx.x >> 6;
    const int row0 = blockIdx.y * 128;
    const int col0 = blockIdx.x * 128;
    const int wr = (wv >> 1) * 64;
    const int wc = (wv & 1) * 64;
    const int li = lane & 15;
    const int g = lane >> 4;
    const int lr = lane >> 2;
    const int lk = (lane & 3) * 8;

    f32x4 acc[4][4];
#pragma unroll
    for (int m = 0; m < 4; ++m)
#pragma unroll
        for (int n = 0; n < 4; ++n) acc[m][n] = (f32x4){0.f, 0.f, 0.f, 0.f};

    for (int k0 = 0; k0 < Kdim; k0 += 32) {
#pragma unroll
        for (int i = 0; i < 2; ++i) {
            int cc = wv * 2 + i;
            const short* ga = A + (size_t)(row0 + cc * 16 + lr) * Kdim + k0 + lk;
            __builtin_amdgcn_global_load_lds(gas(ga), las(&As[cc * 512]), 16, 0, 0);
            const short* gb = Bt + (size_t)(col0 + cc * 16 + lr) * Kdim + k0 + lk;
            __builtin_amdgcn_global_load_lds(gas(gb), las(&Bs[cc * 512]), 16, 0, 0);
        }
        __syncthreads();
        bf16x8 af[4], bfr[4];
#pragma unroll
        for (int m = 0; m < 4; ++m) af[m] = *(const bf16x8*)&As[(wr + 16 * m + li) * 32 + g * 8];
#pragma unroll
        for (int n = 0; n < 4; ++n) bfr[n] = *(const bf16x8*)&Bs[(wc + 16 * n + li) * 32 + g * 8];
#pragma unroll
        for (int m = 0; m < 4; ++m)
#pragma unroll
            for (int n = 0; n < 4; ++n)
                acc[m][n] = __builtin_amdgcn_mfma_f32_16x16x32_bf16(af[m], bfr[n], acc[m][n], 0, 0, 0);
        __syncthreads();
    }

#pragma unroll
    for (int n = 0; n < 4; ++n) {
        int ncol = col0 + wc + 16 * n + li;
        float bv = bias[ncol];
#pragma unroll
        for (int m = 0; m < 4; ++m) {
            int rbase = row0 + wr + 16 * m + 4 * g;
#pragma unroll
            for (int j = 0; j < 4; ++j)
                Cf[(size_t)(rbase + j) * Ndim + ncol] = acc[m][n][j] + bv;
        }
    }
}

// ---------------- causal flash attention v8: merged softmax + K/V double-buffer ----------------
__global__ __launch_bounds__(256, 4) void attn_kernel(
    const short* __restrict__ Qb, const short* __restrict__ Kb,
    const short* __restrict__ Vt, short* __restrict__ Ob) {
    __shared__ __attribute__((aligned(16))) short Kl[2][4096];  // [buf][64 keys][64 d] 16KB
    __shared__ __attribute__((aligned(16))) short Vl[2][4096];  // [buf][64 d][64 keys] 16KB
    const int lane = threadIdx.x & 63;
    const int wv = threadIdx.x >> 6;          // 0..3
    const int l31 = lane & 31;
    const int hi = lane >> 5;                 // 0/1
    const int id = blockIdx.x;
    const int xcd = id & 7;
    const int r_ = id >> 3;                   // 0..127
    const int qt = 15 - (r_ >> 3);            // 15..0 heavy-first
    const int bh = xcd * 8 + (r_ & 7);
    const int bb = bh >> 4, hh = bh & 15;
    const short* Qh = Qb + (size_t)bb * (S_ * E_) + hh * 64;
    const short* Kh = Kb + (size_t)bb * (S_ * E_) + hh * 64;
    const short* Vh = Vt + (size_t)bh * (D_ * S_);
    const float CEXP = 0.18033688011112042f;  // (1/8)*log2(e)

    const int rstage = wv * 8 + (lane >> 3);                      // 0..31
    const int cstage = (((lane & 7) ^ ((lane >> 3) & 7)) << 4);   // inverse swizzle

    const int q0w = qt * 128 + wv * 32;
    const int q = q0w + l31;

    bf16x8 qf[4];
#pragma unroll
    for (int c = 0; c < 4; ++c)
        qf[c] = *(const bf16x8*)&Qh[(size_t)q * E_ + c * 16 + hi * 8];

    f32x16 acc[2];
#pragma unroll
    for (int d = 0; d < 2; ++d)
#pragma unroll
        for (int r = 0; r < 16; ++r) acc[d][r] = 0.f;
    float m = -3e38f, mC = 0.f, l = 0.f;

    const int nw = (q0w + 95) >> 6;          // 64-key tiles this wave computes
    const int nt = (qt * 128 + 191) >> 6;    // tiles staged by block

    auto stage = [&](int it, int buf) {
        const int kt0 = it * 64;
#pragma unroll
        for (int half = 0; half < 2; ++half) {
            const char* gk = (const char*)(Kh + (size_t)(kt0 + half * 32 + rstage) * E_) + cstage;
            __builtin_amdgcn_global_load_lds(gas(gk), las((char*)&Kl[buf][0] + half * 4096 + wv * 1024), 16, 0, 0);
            const char* gv = (const char*)Vh + (size_t)(half * 32 + rstage) * (S_ * 2) + (size_t)kt0 * 2 + cstage;
            __builtin_amdgcn_global_load_lds(gas(gv), las((char*)&Vl[buf][0] + half * 4096 + wv * 1024), 16, 0, 0);
        }
    };

    stage(0, 0);
    __syncthreads();

    for (int it = 0; it < nt; ++it) {
        const int buf = it & 1;
        if (it + 1 < nt) stage(it + 1, buf ^ 1);  // prefetch next tile into other buffer
        if (it < nw) {
            const int kt0 = it * 64;
            const char* Kb_ = (const char*)&Kl[buf][0];
            const char* Vb_ = (const char*)&Vl[buf][0];
            // ---- QK^T both subtiles (swapped): S[key][q] ----
            f32x16 sc0, sc1;
#pragma unroll
            for (int r = 0; r < 16; ++r) { sc0[r] = 0.f; sc1[r] = 0.f; }
#pragma unroll
            for (int c = 0; c < 4; ++c) {
                const int r0 = l31, r1 = 32 + l31;
                bf16x8 kf0 = *(const bf16x8*)(Kb_ + r0 * 128 + ((c * 32 + hi * 16) ^ ((r0 & 7) << 4)));
                bf16x8 kf1 = *(const bf16x8*)(Kb_ + r1 * 128 + ((c * 32 + hi * 16) ^ ((r1 & 7) << 4)));
                sc0 = __builtin_amdgcn_mfma_f32_32x32x16_bf16(kf0, qf[c], sc0, 0, 0, 0);
                sc1 = __builtin_amdgcn_mfma_f32_32x32x16_bf16(kf1, qf[c], sc1, 0, 0, 0);
            }
            // ---- causal mask: needed iff max key (kt0+63) > min q (q0w) ----
            if (kt0 + 63 > q0w) {
                const int kb = kt0 + 4 * hi;
#pragma unroll
                for (int r = 0; r < 16; ++r) {
                    int key = kb + (r & 3) + 8 * (r >> 2);
                    sc0[r] = (key > q) ? -3e38f : sc0[r];
                    sc1[r] = (key + 32 > q) ? -3e38f : sc1[r];
                }
            }
            // ---- row max: 31-op tree + 1 shfl ----
            float tmx[8];
#pragma unroll
            for (int r = 0; r < 8; ++r)
                tmx[r] = fmaxf(fmaxf(sc0[2 * r], sc0[2 * r + 1]),
                               fmaxf(sc1[2 * r], sc1[2 * r + 1]));
            float tm = fmaxf(fmaxf(fmaxf(tmx[0], tmx[1]), fmaxf(tmx[2], tmx[3])),
                             fmaxf(fmaxf(tmx[4], tmx[5]), fmaxf(tmx[6], tmx[7])));
            tm = fmaxf(tm, __shfl_xor(tm, 32, 64));
            // ---- defer-max rescale (THR=16 logits) ----
            bool need = (tm > m + 16.0f);
            if (__ballot((int)need) != 0ull) {
                float mn = fmaxf(m, tm);
                float sf = exp2a((m - mn) * CEXP);
                m = mn; mC = mn * CEXP;
                l *= sf;
#pragma unroll
                for (int d = 0; d < 2; ++d)
#pragma unroll
                    for (int r = 0; r < 16; ++r) acc[d][r] *= sf;
            }
            // ---- p = exp2(s*C - m*C) in place ----
#pragma unroll
            for (int r = 0; r < 16; ++r) {
                sc0[r] = exp2a(fmaf(sc0[r], CEXP, -mC));
                sc1[r] = exp2a(fmaf(sc1[r], CEXP, -mC));
            }
            // ---- one l-reduce ----
            float s0 = 0.f, s1 = 0.f;
#pragma unroll
            for (int r = 0; r < 8; ++r) {
                s0 += sc0[2 * r] + sc0[2 * r + 1];
                s1 += sc1[2 * r] + sc1[2 * r + 1];
            }
            float ls = s0 + s1;
            ls += __shfl_xor(ls, 32, 64);
            l += ls;
            // ---- pack both subtiles -> 4 PV B-frags ----
            const bool lo = (hi == 0);
            bf16x8 pf[4];
#pragma unroll
            for (int s = 0; s < 2; ++s) {
                const f32x16& p = s ? sc1 : sc0;
                unsigned W0 = cvtpk(p[0], p[1]),   W1 = cvtpk(p[2], p[3]);
                unsigned W2 = cvtpk(p[4], p[5]),   W3 = cvtpk(p[6], p[7]);
                unsigned W4 = cvtpk(p[8], p[9]),   W5 = cvtpk(p[10], p[11]);
                unsigned W6 = cvtpk(p[12], p[13]), W7 = cvtpk(p[14], p[15]);
                unsigned xW0 = __shfl_xor(W0, 32, 64), xW1 = __shfl_xor(W1, 32, 64);
                unsigned xW2 = __shfl_xor(W2, 32, 64), xW3 = __shfl_xor(W3, 32, 64);
                unsigned xW4 = __shfl_xor(W4, 32, 64), xW5 = __shfl_xor(W5, 32, 64);
                unsigned xW6 = __shfl_xor(W6, 32, 64), xW7 = __shfl_xor(W7, 32, 64);
                uint4v u1, u2;
                u1[0] = lo ? W0 : xW2;  u1[1] = lo ? W1 : xW3;
                u1[2] = lo ? xW0 : W2;  u1[3] = lo ? xW1 : W3;
                u2[0] = lo ? W4 : xW6;  u2[1] = lo ? W5 : xW7;
                u2[2] = lo ? xW4 : W6;  u2[3] = lo ? xW5 : W7;
                pf[s * 2] = __builtin_bit_cast(bf16x8, u1);
                pf[s * 2 + 1] = __builtin_bit_cast(bf16x8, u2);
            }
            // ---- PV ----
#pragma unroll
            for (int db = 0; db < 2; ++db) {
                const int row = db * 32 + l31;
                const int rsw = (row & 7) << 4;
                const char* vrow = Vb_ + row * 128;
                bf16x8 v0 = *(const bf16x8*)(vrow + ((hi * 16) ^ rsw));
                bf16x8 v1 = *(const bf16x8*)(vrow + ((32 + hi * 16) ^ rsw));
                bf16x8 v2 = *(const bf16x8*)(vrow + ((64 + hi * 16) ^ rsw));
                bf16x8 v3 = *(const bf16x8*)(vrow + ((96 + hi * 16) ^ rsw));
                acc[db] = __builtin_amdgcn_mfma_f32_32x32x16_bf16(v0, pf[0], acc[db], 0, 0, 0);
                acc[db] = __builtin_amdgcn_mfma_f32_32x32x16_bf16(v1, pf[1], acc[db], 0, 0, 0);
                acc[db] = __builtin_amdgcn_mfma_f32_32x32x16_bf16(v2, pf[2], acc[db], 0, 0, 0);
                acc[db] = __builtin_amdgcn_mfma_f32_32x32x16_bf16(v3, pf[3], acc[db], 0, 0, 0);
            }
        }
        __syncthreads();  // implicit vmcnt(0)+lgkmcnt(0): next tile fully staged
    }

    // ---- epilogue ----
    float rl = __builtin_amdgcn_rcpf(l);
    short* orow = Ob + ((size_t)(bb * S_ + q)) * E_ + hh * 64;
#pragma unroll
    for (int db = 0; db < 2; ++db)
#pragma unroll
        for (int rb = 0; rb < 4; ++rb) {
            uint2v pk;
            pk[0] = cvtpk(acc[db][rb * 4 + 0] * rl, acc[db][rb * 4 + 1] * rl);
            pk[1] = cvtpk(acc[db][rb * 4 + 2] * rl, acc[db][rb * 4 + 3] * rl);
            *(uint2v*)&orow[db * 32 + rb * 8 + hi * 4] = pk;
        }
}

extern "C" void kernel_launch(void* const* d_in, const int* in_sizes, int n_in,
                              void* d_out, int out_size, void* d_ws, size_t ws_size,
                              hipStream_t stream) {
    const float* x      = (const float*)d_in[0];
    const float* w_attn = (const float*)d_in[1];
    const float* b_attn = (const float*)d_in[2];
    const float* w_out  = (const float*)d_in[3];
    const float* b_out  = (const float*)d_in[4];
    float* out = (float*)d_out;

    char* ws = (char*)d_ws;
    short* Xbf  = (short*)(ws);                       // 16 MB (reused as attn output)
    short* Wat  = (short*)(ws + (16ull << 20));       // 6 MB  [3072][1024]
    short* Wot  = (short*)(ws + (22ull << 20));       // 2 MB  [1024][1024]
    short* Qb   = (short*)(ws + (24ull << 20));       // 16 MB flat [8192][1024]
    short* Kb   = (short*)(ws + (40ull << 20));       // 16 MB flat [8192][1024]
    short* Vt   = (short*)(ws + (56ull << 20));       // 16 MB [B,H,D,S]
    short* Obuf = Xbf;

    convert_f32_bf16<<<2048, 256, 0, stream>>>(x, Xbf, M_ * E_);
    transpose_convert<<<dim3(N1_ / 32, E_ / 32), dim3(32, 8), 0, stream>>>(w_attn, Wat, E_, N1_);
    transpose_convert<<<dim3(E_ / 32, E_ / 32), dim3(32, 8), 0, stream>>>(w_out, Wot, E_, E_);

    gemm_qkv<<<768, 512, 0, stream>>>(Xbf, Wat, b_attn, Qb, Kb, Vt);

    attn_kernel<<<1024, 256, 0, stream>>>(Qb, Kb, Vt, Obuf);

    gemm_bt_out<<<dim3(E_ / 128, M_ / 128), 256, 0, stream>>>(
        Obuf, Wot, b_out, out, E_, E_);
}

// Round 12
// 176.551 us; speedup vs baseline: 1.0891x; 1.0891x over previous
//
#include <hip/hip_runtime.h>

typedef short bf16x8 __attribute__((ext_vector_type(8)));
typedef float f32x4 __attribute__((ext_vector_type(4)));
typedef float f32x16 __attribute__((ext_vector_type(16)));
typedef float float4v __attribute__((ext_vector_type(4)));
typedef short short4v __attribute__((ext_vector_type(4)));
typedef unsigned uint2v __attribute__((ext_vector_type(2)));
typedef unsigned uint4v __attribute__((ext_vector_type(4)));

#define B_ 4
#define S_ 2048
#define E_ 1024
#define H_ 16
#define D_ 64
#define M_ (B_*S_)      // 8192
#define N1_ (3*E_)      // 3072

__device__ inline short f2bs(float f) {
    unsigned u = __builtin_bit_cast(unsigned, f);
    unsigned r = u + 0x7fffu + ((u >> 16) & 1u);
    return (short)(r >> 16);
}
__device__ inline float exp2a(float x) {
    float r; asm("v_exp_f32 %0, %1" : "=v"(r) : "v"(x)); return r;
}
__device__ inline unsigned cvtpk(float a, float b) {
    unsigned r; asm("v_cvt_pk_bf16_f32 %0, %1, %2" : "=v"(r) : "v"(a), "v"(b)); return r;
}

__device__ inline const __attribute__((address_space(1))) void* gas(const void* p) {
    return (const __attribute__((address_space(1))) void*)p;
}
__device__ inline __attribute__((address_space(3))) void* las(void* p) {
    return (__attribute__((address_space(3))) void*)p;
}

// ---------------- elementwise fp32 -> bf16 ----------------
__global__ void convert_f32_bf16(const float* __restrict__ in, short* __restrict__ out, int n) {
    int tid = blockIdx.x * blockDim.x + threadIdx.x;
    int stride = gridDim.x * blockDim.x;
    for (int i = tid * 4; i < n; i += stride * 4) {
        float4v v = *(const float4v*)&in[i];
        short4v o;
        o[0] = f2bs(v[0]); o[1] = f2bs(v[1]); o[2] = f2bs(v[2]); o[3] = f2bs(v[3]);
        *(short4v*)&out[i] = o;
    }
}

// ---------------- tiled transpose + convert ----------------
__global__ void transpose_convert(const float* __restrict__ in, short* __restrict__ out,
                                  int rows, int cols) {
    __shared__ float t[32][33];
    int bx = blockIdx.x * 32;
    int by = blockIdx.y * 32;
    int tx = threadIdx.x, ty = threadIdx.y;  // (32, 8)
#pragma unroll
    for (int i = 0; i < 4; ++i)
        t[ty + i * 8][tx] = in[(size_t)(by + ty + i * 8) * cols + bx + tx];
    __syncthreads();
#pragma unroll
    for (int i = 0; i < 4; ++i)
        out[(size_t)(bx + ty + i * 8) * rows + by + tx] = f2bs(t[tx][ty + i * 8]);
}

// ================= 256x192 8-phase GEMM (QKV), grid 512 = 2x256 exact =================
// 8 waves (2M x 4N): per-wave 128 rows x 48 cols. BK=64. 112KB LDS dbuf.
// Loads/K-tile: B 3, A-s0 2, A-s1 2 = 7. Counted vmcnt (derivation in journal):
//   P0 stageB | P1 stageA-s0 + VMW(5) | P2 stageA-s1 | P3 VMW(2).
#define MFMA12(Q) \
    _Pragma("unroll") for (int mf = 0; mf < 2; ++mf) \
    _Pragma("unroll") for (int nf = 0; nf < 3; ++nf) { \
        acc[(Q)*2+mf][nf] = __builtin_amdgcn_mfma_f32_16x16x32_bf16(af[mf][0], bfrag[nf][0], acc[(Q)*2+mf][nf], 0, 0, 0); \
        acc[(Q)*2+mf][nf] = __builtin_amdgcn_mfma_f32_16x16x32_bf16(af[mf][1], bfrag[nf][1], acc[(Q)*2+mf][nf], 0, 0, 0); \
    }

#define PHASE(Q, STAGE_STMT, WAITV) do { \
    bf16x8 af[2][2]; \
    _Pragma("unroll") for (int mf = 0; mf < 2; ++mf) \
    _Pragma("unroll") for (int ks = 0; ks < 2; ++ks) { \
        int r = (Q)*32 + mf*16 + li; \
        af[mf][ks] = *(const bf16x8*)(lA + r*128 + ((ks*64 + g*16) ^ ((r & 7) << 4))); \
    } \
    STAGE_STMT; \
    __builtin_amdgcn_s_barrier(); \
    asm volatile("s_waitcnt lgkmcnt(0)" ::: "memory"); \
    __builtin_amdgcn_sched_barrier(0); \
    __builtin_amdgcn_s_setprio(1); \
    MFMA12(Q); \
    __builtin_amdgcn_s_setprio(0); \
    WAITV; \
    __builtin_amdgcn_s_barrier(); \
} while (0)

#define VMW(n) asm volatile("s_waitcnt vmcnt(" #n ")" ::: "memory")
#define NOP_ ((void)0)

__global__ __launch_bounds__(512, 2) void gemm_qkv(
    const short* __restrict__ A, const short* __restrict__ Bt,
    const float* __restrict__ bias,
    short* __restrict__ Qb, short* __restrict__ Kb, short* __restrict__ Vt) {
    __shared__ __attribute__((aligned(16))) short ldsA[2][16384];  // [buf][256 rows x 64k] row-major
    __shared__ __attribute__((aligned(16))) short ldsB[2][12288];  // [buf][192 rows x 64k]
    const int tid = threadIdx.x;
    const int lane = tid & 63;
    const int wid = tid >> 6;
    const int li = lane & 15, g = lane >> 4;
    const int wr = wid >> 2, wc = wid & 3;
    const int Kdim = E_;       // 1024
    const int NT = Kdim >> 6;  // 16 K-tiles

    // bijective XCD swizzle: nwg=512, 512/8=64
    const int id = blockIdx.x;
    const int swz = (id & 7) * 64 + (id >> 3);
    const int bx = swz & 15, by = swz >> 4;      // 16 col-tiles, 32 row-tiles
    const int row0 = by * 256, col0 = bx * 192;

    // staging lane geometry: linear LDS dest (64-row unit = 8KB), inverse-swizzled src
    const int rstage = wid * 8 + (lane >> 3);                     // 0..63
    const int cstage = (((lane & 7) ^ ((lane >> 3) & 7)) << 4);

    auto stageA = [&](int buf, int kt, int seg) {
#pragma unroll
        for (int h = 0; h < 2; ++h) {
            const char* src = (const char*)A +
                ((size_t)(row0 + h * 128 + seg * 64 + rstage) * Kdim + kt * 64) * 2 + cstage;
            char* dst = (char*)&ldsA[buf][0] + (h * 2 + seg) * 8192 + wid * 1024;
            __builtin_amdgcn_global_load_lds(gas(src), las(dst), 16, 0, 0);
        }
    };
    auto stageB = [&](int buf, int kt) {
#pragma unroll
        for (int i = 0; i < 3; ++i) {
            const char* src = (const char*)Bt +
                ((size_t)(col0 + i * 64 + rstage) * Kdim + kt * 64) * 2 + cstage;
            char* dst = (char*)&ldsB[buf][0] + i * 8192 + wid * 1024;
            __builtin_amdgcn_global_load_lds(gas(src), las(dst), 16, 0, 0);
        }
    };

    f32x4 acc[8][3];
#pragma unroll
    for (int m = 0; m < 8; ++m)
#pragma unroll
        for (int n = 0; n < 3; ++n) acc[m][n] = (f32x4){0.f, 0.f, 0.f, 0.f};

    // prologue: tile 0 -> buf 0, full drain (once)
    stageB(0, 0);
    stageA(0, 0, 0);
    stageA(0, 0, 1);
    asm volatile("s_waitcnt vmcnt(0)" ::: "memory");
    __syncthreads();

    for (int t = 0; t < NT; ++t) {
        const int cur = t & 1;
        const int nb = cur ^ 1;
        const int tn = t + 1;
        const bool st = (tn < NT);
        const char* lA = (const char*)&ldsA[cur][0] + wr * 16384;  // 128-row half
        const char* lB = (const char*)&ldsB[cur][0];

        bf16x8 bfrag[3][2];
#pragma unroll
        for (int nf = 0; nf < 3; ++nf)
#pragma unroll
            for (int ks = 0; ks < 2; ++ks) {
                int r = wc * 48 + nf * 16 + li;
                bfrag[nf][ks] = *(const bf16x8*)(lB + r * 128 + ((ks * 64 + g * 16) ^ ((r & 7) << 4)));
            }
        if (st) {
            PHASE(0, stageB(nb, tn), NOP_);
            PHASE(1, stageA(nb, tn, 0), VMW(5));
            PHASE(2, stageA(nb, tn, 1), NOP_);
            PHASE(3, NOP_, VMW(2));
        } else {
            PHASE(0, NOP_, NOP_);
            PHASE(1, NOP_, VMW(0));
            PHASE(2, NOP_, NOP_);
            PHASE(3, NOP_, NOP_);
        }
    }

    // ---- epilogue (C layout: col = lane&15, row = (lane>>4)*4 + j) ----
    // 192-wide tiles straddle Q/K/V boundaries; each 16-col group is boundary-aligned.
#pragma unroll
    for (int nf = 0; nf < 3; ++nf) {
        int ncolg = col0 + wc * 48 + nf * 16 + li;
        float bv = bias[ncolg];
        int part = ncolg >> 10;
        int rem = ncolg & 1023;
        if (part < 2) {
            short* Dst = (part == 0) ? Qb : Kb;
#pragma unroll
            for (int mi = 0; mi < 8; ++mi) {
                int rbase = row0 + wr * 128 + mi * 16 + 4 * g;
#pragma unroll
                for (int j = 0; j < 4; ++j)
                    Dst[(size_t)(rbase + j) * E_ + rem] = f2bs(acc[mi][nf][j] + bv);
            }
        } else {
            int h = rem >> 6, d = rem & 63;
#pragma unroll
            for (int mi = 0; mi < 8; ++mi) {
                int s0 = row0 + wr * 128 + mi * 16 + 4 * g;
                int bb2 = s0 >> 11;
                int ss = s0 & 2047;
                uint2v p;
                p[0] = cvtpk(acc[mi][nf][0] + bv, acc[mi][nf][1] + bv);
                p[1] = cvtpk(acc[mi][nf][2] + bv, acc[mi][nf][3] + bv);
                *(uint2v*)&Vt[((size_t)(bb2 * H_ + h) * D_ + d) * S_ + ss] = p;
            }
        }
    }
}

// ---------------- bf16 GEMM, 128x128 tile (out-proj) ----------------
__global__ __launch_bounds__(256, 2) void gemm_bt_out(
    const short* __restrict__ A, const short* __restrict__ Bt,
    const float* __restrict__ bias, float* __restrict__ Cf,
    int Kdim, int Ndim) {
    __shared__ __attribute__((aligned(16))) short As[128 * 32];
    __shared__ __attribute__((aligned(16))) short Bs[128 * 32];
    const int lane = threadIdx.x & 63;
    const int wv = threadIdx.x >> 6;
    const int row0 = blockIdx.y * 128;
    const int col0 = blockIdx.x * 128;
    const int wr = (wv >> 1) * 64;
    const int wc = (wv & 1) * 64;
    const int li = lane & 15;
    const int g = lane >> 4;
    const int lr = lane >> 2;
    const int lk = (lane & 3) * 8;

    f32x4 acc[4][4];
#pragma unroll
    for (int m = 0; m < 4; ++m)
#pragma unroll
        for (int n = 0; n < 4; ++n) acc[m][n] = (f32x4){0.f, 0.f, 0.f, 0.f};

    for (int k0 = 0; k0 < Kdim; k0 += 32) {
#pragma unroll
        for (int i = 0; i < 2; ++i) {
            int cc = wv * 2 + i;
            const short* ga = A + (size_t)(row0 + cc * 16 + lr) * Kdim + k0 + lk;
            __builtin_amdgcn_global_load_lds(gas(ga), las(&As[cc * 512]), 16, 0, 0);
            const short* gb = Bt + (size_t)(col0 + cc * 16 + lr) * Kdim + k0 + lk;
            __builtin_amdgcn_global_load_lds(gas(gb), las(&Bs[cc * 512]), 16, 0, 0);
        }
        __syncthreads();
        bf16x8 af[4], bfr[4];
#pragma unroll
        for (int m = 0; m < 4; ++m) af[m] = *(const bf16x8*)&As[(wr + 16 * m + li) * 32 + g * 8];
#pragma unroll
        for (int n = 0; n < 4; ++n) bfr[n] = *(const bf16x8*)&Bs[(wc + 16 * n + li) * 32 + g * 8];
#pragma unroll
        for (int m = 0; m < 4; ++m)
#pragma unroll
            for (int n = 0; n < 4; ++n)
                acc[m][n] = __builtin_amdgcn_mfma_f32_16x16x32_bf16(af[m], bfr[n], acc[m][n], 0, 0, 0);
        __syncthreads();
    }

#pragma unroll
    for (int n = 0; n < 4; ++n) {
        int ncol = col0 + wc + 16 * n + li;
        float bv = bias[ncol];
#pragma unroll
        for (int m = 0; m < 4; ++m) {
            int rbase = row0 + wr + 16 * m + 4 * g;
#pragma unroll
            for (int j = 0; j < 4; ++j)
                Cf[(size_t)(rbase + j) * Ndim + ncol] = acc[m][n][j] + bv;
        }
    }
}

// ---------------- causal flash attention v7b (R10 verified): merged 64-key softmax ----------------
__global__ __launch_bounds__(256, 4) void attn_kernel(
    const short* __restrict__ Qb, const short* __restrict__ Kb,
    const short* __restrict__ Vt, short* __restrict__ Ob) {
    __shared__ __attribute__((aligned(16))) short Kl[4096];  // [64 keys][64 d] 8KB
    __shared__ __attribute__((aligned(16))) short Vl[4096];  // [64 d][64 keys] 8KB
    const int lane = threadIdx.x & 63;
    const int wv = threadIdx.x >> 6;          // 0..3
    const int l31 = lane & 31;
    const int hi = lane >> 5;                 // 0/1
    const int id = blockIdx.x;
    const int xcd = id & 7;
    const int r_ = id >> 3;                   // 0..127
    const int qt = 15 - (r_ >> 3);            // 15..0 heavy-first
    const int bh = xcd * 8 + (r_ & 7);
    const int bb = bh >> 4, hh = bh & 15;
    const short* Qh = Qb + (size_t)bb * (S_ * E_) + hh * 64;
    const short* Kh = Kb + (size_t)bb * (S_ * E_) + hh * 64;
    const short* Vh = Vt + (size_t)bh * (D_ * S_);
    const float CEXP = 0.18033688011112042f;  // (1/8)*log2(e)

    const int rstage = wv * 8 + (lane >> 3);                      // 0..31
    const int cstage = (((lane & 7) ^ ((lane >> 3) & 7)) << 4);   // inverse swizzle

    const int q0w = qt * 128 + wv * 32;
    const int q = q0w + l31;

    bf16x8 qf[4];
#pragma unroll
    for (int c = 0; c < 4; ++c)
        qf[c] = *(const bf16x8*)&Qh[(size_t)q * E_ + c * 16 + hi * 8];

    f32x16 acc[2];
#pragma unroll
    for (int d = 0; d < 2; ++d)
#pragma unroll
        for (int r = 0; r < 16; ++r) acc[d][r] = 0.f;
    float m = -3e38f, mC = 0.f, l = 0.f;

    const int nw = (q0w + 95) >> 6;          // 64-key tiles this wave computes
    const int nt = (qt * 128 + 191) >> 6;    // tiles staged by block

    for (int it = 0; it < nt; ++it) {
        const int kt0 = it * 64;
#pragma unroll
        for (int half = 0; half < 2; ++half) {
            const char* gk = (const char*)(Kh + (size_t)(kt0 + half * 32 + rstage) * E_) + cstage;
            __builtin_amdgcn_global_load_lds(gas(gk), las((char*)Kl + half * 4096 + wv * 1024), 16, 0, 0);
            const char* gv = (const char*)Vh + (size_t)(half * 32 + rstage) * (S_ * 2) + (size_t)kt0 * 2 + cstage;
            __builtin_amdgcn_global_load_lds(gas(gv), las((char*)Vl + half * 4096 + wv * 1024), 16, 0, 0);
        }
        __syncthreads();
        if (it < nw) {
            f32x16 sc0, sc1;
#pragma unroll
            for (int r = 0; r < 16; ++r) { sc0[r] = 0.f; sc1[r] = 0.f; }
#pragma unroll
            for (int c = 0; c < 4; ++c) {
                const int r0 = l31, r1 = 32 + l31;
                bf16x8 kf0 = *(const bf16x8*)((const char*)Kl + r0 * 128 +
                                              ((c * 32 + hi * 16) ^ ((r0 & 7) << 4)));
                bf16x8 kf1 = *(const bf16x8*)((const char*)Kl + r1 * 128 +
                                              ((c * 32 + hi * 16) ^ ((r1 & 7) << 4)));
                sc0 = __builtin_amdgcn_mfma_f32_32x32x16_bf16(kf0, qf[c], sc0, 0, 0, 0);
                sc1 = __builtin_amdgcn_mfma_f32_32x32x16_bf16(kf1, qf[c], sc1, 0, 0, 0);
            }
            if (kt0 + 63 > q0w) {
                const int kb = kt0 + 4 * hi;
#pragma unroll
                for (int r = 0; r < 16; ++r) {
                    int key = kb + (r & 3) + 8 * (r >> 2);
                    sc0[r] = (key > q) ? -3e38f : sc0[r];
                    sc1[r] = (key + 32 > q) ? -3e38f : sc1[r];
                }
            }
            float tmx[8];
#pragma unroll
            for (int r = 0; r < 8; ++r)
                tmx[r] = fmaxf(fmaxf(sc0[2 * r], sc0[2 * r + 1]),
                               fmaxf(sc1[2 * r], sc1[2 * r + 1]));
            float tm = fmaxf(fmaxf(fmaxf(tmx[0], tmx[1]), fmaxf(tmx[2], tmx[3])),
                             fmaxf(fmaxf(tmx[4], tmx[5]), fmaxf(tmx[6], tmx[7])));
            tm = fmaxf(tm, __shfl_xor(tm, 32, 64));
            bool need = (tm > m + 16.0f);
            if (__ballot((int)need) != 0ull) {
                float mn = fmaxf(m, tm);
                float sf = exp2a((m - mn) * CEXP);
                m = mn; mC = mn * CEXP;
                l *= sf;
#pragma unroll
                for (int d = 0; d < 2; ++d)
#pragma unroll
                    for (int r = 0; r < 16; ++r) acc[d][r] *= sf;
            }
#pragma unroll
            for (int r = 0; r < 16; ++r) {
                sc0[r] = exp2a(fmaf(sc0[r], CEXP, -mC));
                sc1[r] = exp2a(fmaf(sc1[r], CEXP, -mC));
            }
            float s0 = 0.f, s1 = 0.f;
#pragma unroll
            for (int r = 0; r < 8; ++r) {
                s0 += sc0[2 * r] + sc0[2 * r + 1];
                s1 += sc1[2 * r] + sc1[2 * r + 1];
            }
            float ls = s0 + s1;
            ls += __shfl_xor(ls, 32, 64);
            l += ls;
            const bool lo = (hi == 0);
            bf16x8 pf[4];
#pragma unroll
            for (int s = 0; s < 2; ++s) {
                const f32x16& p = s ? sc1 : sc0;
                unsigned W0 = cvtpk(p[0], p[1]),   W1 = cvtpk(p[2], p[3]);
                unsigned W2 = cvtpk(p[4], p[5]),   W3 = cvtpk(p[6], p[7]);
                unsigned W4 = cvtpk(p[8], p[9]),   W5 = cvtpk(p[10], p[11]);
                unsigned W6 = cvtpk(p[12], p[13]), W7 = cvtpk(p[14], p[15]);
                unsigned xW0 = __shfl_xor(W0, 32, 64), xW1 = __shfl_xor(W1, 32, 64);
                unsigned xW2 = __shfl_xor(W2, 32, 64), xW3 = __shfl_xor(W3, 32, 64);
                unsigned xW4 = __shfl_xor(W4, 32, 64), xW5 = __shfl_xor(W5, 32, 64);
                unsigned xW6 = __shfl_xor(W6, 32, 64), xW7 = __shfl_xor(W7, 32, 64);
                uint4v u1, u2;
                u1[0] = lo ? W0 : xW2;  u1[1] = lo ? W1 : xW3;
                u1[2] = lo ? xW0 : W2;  u1[3] = lo ? xW1 : W3;
                u2[0] = lo ? W4 : xW6;  u2[1] = lo ? W5 : xW7;
                u2[2] = lo ? xW4 : W6;  u2[3] = lo ? xW5 : W7;
                pf[s * 2] = __builtin_bit_cast(bf16x8, u1);
                pf[s * 2 + 1] = __builtin_bit_cast(bf16x8, u2);
            }
#pragma unroll
            for (int db = 0; db < 2; ++db) {
                const int row = db * 32 + l31;
                const int rsw = (row & 7) << 4;
                const char* vrow = (const char*)Vl + row * 128;
                bf16x8 v0 = *(const bf16x8*)(vrow + ((hi * 16) ^ rsw));
                bf16x8 v1 = *(const bf16x8*)(vrow + ((32 + hi * 16) ^ rsw));
                bf16x8 v2 = *(const bf16x8*)(vrow + ((64 + hi * 16) ^ rsw));
                bf16x8 v3 = *(const bf16x8*)(vrow + ((96 + hi * 16) ^ rsw));
                acc[db] = __builtin_amdgcn_mfma_f32_32x32x16_bf16(v0, pf[0], acc[db], 0, 0, 0);
                acc[db] = __builtin_amdgcn_mfma_f32_32x32x16_bf16(v1, pf[1], acc[db], 0, 0, 0);
                acc[db] = __builtin_amdgcn_mfma_f32_32x32x16_bf16(v2, pf[2], acc[db], 0, 0, 0);
                acc[db] = __builtin_amdgcn_mfma_f32_32x32x16_bf16(v3, pf[3], acc[db], 0, 0, 0);
            }
        }
        __syncthreads();
    }

    float rl = __builtin_amdgcn_rcpf(l);
    short* orow = Ob + ((size_t)(bb * S_ + q)) * E_ + hh * 64;
#pragma unroll
    for (int db = 0; db < 2; ++db)
#pragma unroll
        for (int rb = 0; rb < 4; ++rb) {
            uint2v pk;
            pk[0] = cvtpk(acc[db][rb * 4 + 0] * rl, acc[db][rb * 4 + 1] * rl);
            pk[1] = cvtpk(acc[db][rb * 4 + 2] * rl, acc[db][rb * 4 + 3] * rl);
            *(uint2v*)&orow[db * 32 + rb * 8 + hi * 4] = pk;
        }
}

extern "C" void kernel_launch(void* const* d_in, const int* in_sizes, int n_in,
                              void* d_out, int out_size, void* d_ws, size_t ws_size,
                              hipStream_t stream) {
    const float* x      = (const float*)d_in[0];
    const float* w_attn = (const float*)d_in[1];
    const float* b_attn = (const float*)d_in[2];
    const float* w_out  = (const float*)d_in[3];
    const float* b_out  = (const float*)d_in[4];
    float* out = (float*)d_out;

    char* ws = (char*)d_ws;
    short* Xbf  = (short*)(ws);                       // 16 MB (reused as attn output)
    short* Wat  = (short*)(ws + (16ull << 20));       // 6 MB  [3072][1024]
    short* Wot  = (short*)(ws + (22ull << 20));       // 2 MB  [1024][1024]
    short* Qb   = (short*)(ws + (24ull << 20));       // 16 MB flat [8192][1024]
    short* Kb   = (short*)(ws + (40ull << 20));       // 16 MB flat [8192][1024]
    short* Vt   = (short*)(ws + (56ull << 20));       // 16 MB [B,H,D,S]
    short* Obuf = Xbf;

    convert_f32_bf16<<<2048, 256, 0, stream>>>(x, Xbf, M_ * E_);
    transpose_convert<<<dim3(N1_ / 32, E_ / 32), dim3(32, 8), 0, stream>>>(w_attn, Wat, E_, N1_);
    transpose_convert<<<dim3(E_ / 32, E_ / 32), dim3(32, 8), 0, stream>>>(w_out, Wot, E_, E_);

    gemm_qkv<<<512, 512, 0, stream>>>(Xbf, Wat, b_attn, Qb, Kb, Vt);

    attn_kernel<<<1024, 256, 0, stream>>>(Qb, Kb, Vt, Obuf);

    gemm_bt_out<<<dim3(E_ / 128, M_ / 128), 256, 0, stream>>>(
        Obuf, Wot, b_out, out, E_, E_);
}

// Round 13
// 175.576 us; speedup vs baseline: 1.0952x; 1.0056x over previous
//
#include <hip/hip_runtime.h>

typedef short bf16x8 __attribute__((ext_vector_type(8)));
typedef float f32x4 __attribute__((ext_vector_type(4)));
typedef float f32x16 __attribute__((ext_vector_type(16)));
typedef float float4v __attribute__((ext_vector_type(4)));
typedef short short4v __attribute__((ext_vector_type(4)));
typedef unsigned uint2v __attribute__((ext_vector_type(2)));
typedef unsigned uint4v __attribute__((ext_vector_type(4)));

#define B_ 4
#define S_ 2048
#define E_ 1024
#define H_ 16
#define D_ 64
#define M_ (B_*S_)      // 8192
#define N1_ (3*E_)      // 3072

__device__ inline short f2bs(float f) {
    unsigned u = __builtin_bit_cast(unsigned, f);
    unsigned r = u + 0x7fffu + ((u >> 16) & 1u);
    return (short)(r >> 16);
}
__device__ inline float exp2a(float x) {
    float r; asm("v_exp_f32 %0, %1" : "=v"(r) : "v"(x)); return r;
}
__device__ inline unsigned cvtpk(float a, float b) {
    unsigned r; asm("v_cvt_pk_bf16_f32 %0, %1, %2" : "=v"(r) : "v"(a), "v"(b)); return r;
}

__device__ inline const __attribute__((address_space(1))) void* gas(const void* p) {
    return (const __attribute__((address_space(1))) void*)p;
}
__device__ inline __attribute__((address_space(3))) void* las(void* p) {
    return (__attribute__((address_space(3))) void*)p;
}

// ---------------- elementwise fp32 -> bf16 ----------------
__global__ void convert_f32_bf16(const float* __restrict__ in, short* __restrict__ out, int n) {
    int tid = blockIdx.x * blockDim.x + threadIdx.x;
    int stride = gridDim.x * blockDim.x;
    for (int i = tid * 4; i < n; i += stride * 4) {
        float4v v = *(const float4v*)&in[i];
        short4v o;
        o[0] = f2bs(v[0]); o[1] = f2bs(v[1]); o[2] = f2bs(v[2]); o[3] = f2bs(v[3]);
        *(short4v*)&out[i] = o;
    }
}

// ---------------- tiled transpose + convert ----------------
__global__ void transpose_convert(const float* __restrict__ in, short* __restrict__ out,
                                  int rows, int cols) {
    __shared__ float t[32][33];
    int bx = blockIdx.x * 32;
    int by = blockIdx.y * 32;
    int tx = threadIdx.x, ty = threadIdx.y;  // (32, 8)
#pragma unroll
    for (int i = 0; i < 4; ++i)
        t[ty + i * 8][tx] = in[(size_t)(by + ty + i * 8) * cols + bx + tx];
    __syncthreads();
#pragma unroll
    for (int i = 0; i < 4; ++i)
        out[(size_t)(bx + ty + i * 8) * rows + by + tx] = f2bs(t[tx][ty + i * 8]);
}

// ================= 256x192 8-phase GEMM (QKV), grid 512 = 2x256 exact =================
// Stage-early: ALL 7 loads for tile t+1 issue at P0. VMW(7)@P1 drains A-s1(t);
// VMW(2)@P3 drains B(t+1)+A-s0(t+1), leaves A-s1(t+1) in flight.
#define MFMA12(Q) \
    _Pragma("unroll") for (int mf = 0; mf < 2; ++mf) \
    _Pragma("unroll") for (int nf = 0; nf < 3; ++nf) { \
        acc[(Q)*2+mf][nf] = __builtin_amdgcn_mfma_f32_16x16x32_bf16(af[mf][0], bfrag[nf][0], acc[(Q)*2+mf][nf], 0, 0, 0); \
        acc[(Q)*2+mf][nf] = __builtin_amdgcn_mfma_f32_16x16x32_bf16(af[mf][1], bfrag[nf][1], acc[(Q)*2+mf][nf], 0, 0, 0); \
    }

#define PHASE(Q, STAGE_STMT, WAITV) do { \
    bf16x8 af[2][2]; \
    _Pragma("unroll") for (int mf = 0; mf < 2; ++mf) \
    _Pragma("unroll") for (int ks = 0; ks < 2; ++ks) { \
        int r = (Q)*32 + mf*16 + li; \
        af[mf][ks] = *(const bf16x8*)(lA + r*128 + ((ks*64 + g*16) ^ ((r & 7) << 4))); \
    } \
    STAGE_STMT; \
    __builtin_amdgcn_s_barrier(); \
    asm volatile("s_waitcnt lgkmcnt(0)" ::: "memory"); \
    __builtin_amdgcn_sched_barrier(0); \
    __builtin_amdgcn_s_setprio(1); \
    MFMA12(Q); \
    __builtin_amdgcn_s_setprio(0); \
    WAITV; \
    __builtin_amdgcn_s_barrier(); \
} while (0)

#define VMW(n) asm volatile("s_waitcnt vmcnt(" #n ")" ::: "memory")
#define NOP_ ((void)0)

__global__ __launch_bounds__(512, 2) void gemm_qkv(
    const short* __restrict__ A, const short* __restrict__ Bt,
    const float* __restrict__ bias,
    short* __restrict__ Qb, short* __restrict__ Kb, short* __restrict__ Vt) {
    __shared__ __attribute__((aligned(16))) short ldsA[2][16384];  // [buf][256 rows x 64k]
    __shared__ __attribute__((aligned(16))) short ldsB[2][12288];  // [buf][192 rows x 64k]
    const int tid = threadIdx.x;
    const int lane = tid & 63;
    const int wid = tid >> 6;
    const int li = lane & 15, g = lane >> 4;
    const int wr = wid >> 2, wc = wid & 3;
    const int Kdim = E_;       // 1024
    const int NT = Kdim >> 6;  // 16 K-tiles

    // bijective XCD swizzle: nwg=512, 512/8=64
    const int id = blockIdx.x;
    const int swz = (id & 7) * 64 + (id >> 3);
    const int bx = swz & 15, by = swz >> 4;
    const int row0 = by * 256, col0 = bx * 192;

    const int rstage = wid * 8 + (lane >> 3);
    const int cstage = (((lane & 7) ^ ((lane >> 3) & 7)) << 4);

    auto stageA = [&](int buf, int kt, int seg) {
#pragma unroll
        for (int h = 0; h < 2; ++h) {
            const char* src = (const char*)A +
                ((size_t)(row0 + h * 128 + seg * 64 + rstage) * Kdim + kt * 64) * 2 + cstage;
            char* dst = (char*)&ldsA[buf][0] + (h * 2 + seg) * 8192 + wid * 1024;
            __builtin_amdgcn_global_load_lds(gas(src), las(dst), 16, 0, 0);
        }
    };
    auto stageB = [&](int buf, int kt) {
#pragma unroll
        for (int i = 0; i < 3; ++i) {
            const char* src = (const char*)Bt +
                ((size_t)(col0 + i * 64 + rstage) * Kdim + kt * 64) * 2 + cstage;
            char* dst = (char*)&ldsB[buf][0] + i * 8192 + wid * 1024;
            __builtin_amdgcn_global_load_lds(gas(src), las(dst), 16, 0, 0);
        }
    };

    f32x4 acc[8][3];
#pragma unroll
    for (int m = 0; m < 8; ++m)
#pragma unroll
        for (int n = 0; n < 3; ++n) acc[m][n] = (f32x4){0.f, 0.f, 0.f, 0.f};

    stageB(0, 0);
    stageA(0, 0, 0);
    stageA(0, 0, 1);
    asm volatile("s_waitcnt vmcnt(0)" ::: "memory");
    __syncthreads();

    for (int t = 0; t < NT; ++t) {
        const int cur = t & 1;
        const int nb = cur ^ 1;
        const int tn = t + 1;
        const bool st = (tn < NT);
        const char* lA = (const char*)&ldsA[cur][0] + wr * 16384;
        const char* lB = (const char*)&ldsB[cur][0];

        bf16x8 bfrag[3][2];
#pragma unroll
        for (int nf = 0; nf < 3; ++nf)
#pragma unroll
            for (int ks = 0; ks < 2; ++ks) {
                int r = wc * 48 + nf * 16 + li;
                bfrag[nf][ks] = *(const bf16x8*)(lB + r * 128 + ((ks * 64 + g * 16) ^ ((r & 7) << 4)));
            }
        if (st) {
            PHASE(0, { stageB(nb, tn); stageA(nb, tn, 0); stageA(nb, tn, 1); }, NOP_);
            PHASE(1, NOP_, VMW(7));
            PHASE(2, NOP_, NOP_);
            PHASE(3, NOP_, VMW(2));
        } else {
            PHASE(0, NOP_, NOP_);
            PHASE(1, NOP_, VMW(0));
            PHASE(2, NOP_, NOP_);
            PHASE(3, NOP_, NOP_);
        }
    }

    // ---- epilogue (C layout: col = lane&15, row = (lane>>4)*4 + j) ----
#pragma unroll
    for (int nf = 0; nf < 3; ++nf) {
        int ncolg = col0 + wc * 48 + nf * 16 + li;
        float bv = bias[ncolg];
        int part = ncolg >> 10;
        int rem = ncolg & 1023;
        if (part < 2) {
            short* Dst = (part == 0) ? Qb : Kb;
#pragma unroll
            for (int mi = 0; mi < 8; ++mi) {
                int rbase = row0 + wr * 128 + mi * 16 + 4 * g;
#pragma unroll
                for (int j = 0; j < 4; ++j)
                    Dst[(size_t)(rbase + j) * E_ + rem] = f2bs(acc[mi][nf][j] + bv);
            }
        } else {
            int h = rem >> 6, d = rem & 63;
#pragma unroll
            for (int mi = 0; mi < 8; ++mi) {
                int s0 = row0 + wr * 128 + mi * 16 + 4 * g;
                int bb2 = s0 >> 11;
                int ss = s0 & 2047;
                uint2v p;
                p[0] = cvtpk(acc[mi][nf][0] + bv, acc[mi][nf][1] + bv);
                p[1] = cvtpk(acc[mi][nf][2] + bv, acc[mi][nf][3] + bv);
                *(uint2v*)&Vt[((size_t)(bb2 * H_ + h) * D_ + d) * S_ + ss] = p;
            }
        }
    }
}

// ================= 256x128 8-phase GEMM (out-proj), grid 256 = 1x256 exact =================
// R11-verified body (BN=128). B weight is 2MB -> L2-resident, no FETCH blowup here.
#define MFMA8(Q) \
    _Pragma("unroll") for (int mf = 0; mf < 2; ++mf) \
    _Pragma("unroll") for (int nf = 0; nf < 2; ++nf) { \
        acc[(Q)*2+mf][nf] = __builtin_amdgcn_mfma_f32_16x16x32_bf16(af[mf][0], bfrag[nf][0], acc[(Q)*2+mf][nf], 0, 0, 0); \
        acc[(Q)*2+mf][nf] = __builtin_amdgcn_mfma_f32_16x16x32_bf16(af[mf][1], bfrag[nf][1], acc[(Q)*2+mf][nf], 0, 0, 0); \
    }

#define PHASE8(Q, STAGE_STMT, WAITV) do { \
    bf16x8 af[2][2]; \
    _Pragma("unroll") for (int mf = 0; mf < 2; ++mf) \
    _Pragma("unroll") for (int ks = 0; ks < 2; ++ks) { \
        int r = (Q)*32 + mf*16 + li; \
        af[mf][ks] = *(const bf16x8*)(lA + r*128 + ((ks*64 + g*16) ^ ((r & 7) << 4))); \
    } \
    STAGE_STMT; \
    __builtin_amdgcn_s_barrier(); \
    asm volatile("s_waitcnt lgkmcnt(0)" ::: "memory"); \
    __builtin_amdgcn_sched_barrier(0); \
    __builtin_amdgcn_s_setprio(1); \
    MFMA8(Q); \
    __builtin_amdgcn_s_setprio(0); \
    WAITV; \
    __builtin_amdgcn_s_barrier(); \
} while (0)

__global__ __launch_bounds__(512, 2) void gemm_out8(
    const short* __restrict__ A, const short* __restrict__ Bt,
    const float* __restrict__ bias, float* __restrict__ Cf) {
    __shared__ __attribute__((aligned(16))) short ldsA[2][2][2][4096];  // [buf][half][seg][64x64]
    __shared__ __attribute__((aligned(16))) short ldsB[2][8192];        // [buf][128x64]
    const int tid = threadIdx.x;
    const int lane = tid & 63;
    const int wid = tid >> 6;
    const int li = lane & 15, g = lane >> 4;
    const int wr = wid >> 2, wc = wid & 3;
    const int Kdim = E_;       // 1024
    const int NT = Kdim >> 6;  // 16

    // bijective XCD swizzle: nwg=256, 256/8=32
    const int id = blockIdx.x;
    const int swz = (id & 7) * 32 + (id >> 3);
    const int bx = swz & 7, by = swz >> 3;       // 8 col-tiles, 32 row-tiles
    const int row0 = by * 256, col0 = bx * 128;

    const int rstage = wid * 8 + (lane >> 3);
    const int cstage = (((lane & 7) ^ ((lane >> 3) & 7)) << 4);

    auto stageA = [&](int buf, int kt, int seg) {
#pragma unroll
        for (int h = 0; h < 2; ++h) {
            const char* src = (const char*)A +
                ((size_t)(row0 + h * 128 + seg * 64 + rstage) * Kdim + kt * 64) * 2 + cstage;
            char* dst = (char*)&ldsA[buf][h][seg][0] + wid * 1024;
            __builtin_amdgcn_global_load_lds(gas(src), las(dst), 16, 0, 0);
        }
    };
    auto stageB = [&](int buf, int kt) {
#pragma unroll
        for (int i = 0; i < 2; ++i) {
            const char* src = (const char*)Bt +
                ((size_t)(col0 + i * 64 + rstage) * Kdim + kt * 64) * 2 + cstage;
            char* dst = (char*)&ldsB[buf][0] + i * 8192 + wid * 1024;
            __builtin_amdgcn_global_load_lds(gas(src), las(dst), 16, 0, 0);
        }
    };

    f32x4 acc[8][2];
#pragma unroll
    for (int m = 0; m < 8; ++m)
#pragma unroll
        for (int n = 0; n < 2; ++n) acc[m][n] = (f32x4){0.f, 0.f, 0.f, 0.f};

    stageB(0, 0);
    stageA(0, 0, 0);
    stageA(0, 0, 1);
    asm volatile("s_waitcnt vmcnt(0)" ::: "memory");
    __syncthreads();

    for (int t = 0; t < NT; ++t) {
        const int cur = t & 1;
        const int nb = cur ^ 1;
        const int tn = t + 1;
        const bool st = (tn < NT);
        const char* lA = (const char*)&ldsA[cur][wr][0][0];
        const char* lB = (const char*)&ldsB[cur][0];

        bf16x8 bfrag[2][2];
#pragma unroll
        for (int nf = 0; nf < 2; ++nf)
#pragma unroll
            for (int ks = 0; ks < 2; ++ks) {
                int r = wc * 32 + nf * 16 + li;
                bfrag[nf][ks] = *(const bf16x8*)(lB + r * 128 + ((ks * 64 + g * 16) ^ ((r & 7) << 4)));
            }
        if (st) {
            PHASE8(0, stageB(nb, tn), NOP_);
            PHASE8(1, stageA(nb, tn, 0), VMW(4));
            PHASE8(2, stageA(nb, tn, 1), NOP_);
            PHASE8(3, NOP_, VMW(2));
        } else {
            PHASE8(0, NOP_, NOP_);
            PHASE8(1, NOP_, VMW(0));
            PHASE8(2, NOP_, NOP_);
            PHASE8(3, NOP_, NOP_);
        }
    }

    // ---- epilogue: fp32 + bias, coalesced 64B lines ----
#pragma unroll
    for (int nf = 0; nf < 2; ++nf) {
        int ncol = col0 + wc * 32 + nf * 16 + li;
        float bv = bias[ncol];
#pragma unroll
        for (int mi = 0; mi < 8; ++mi) {
            int rbase = row0 + wr * 128 + mi * 16 + 4 * g;
#pragma unroll
            for (int j = 0; j < 4; ++j)
                Cf[(size_t)(rbase + j) * E_ + ncol] = acc[mi][nf][j] + bv;
        }
    }
}

// ---------------- causal flash attention v7b (R10/R12 verified) ----------------
__global__ __launch_bounds__(256, 4) void attn_kernel(
    const short* __restrict__ Qb, const short* __restrict__ Kb,
    const short* __restrict__ Vt, short* __restrict__ Ob) {
    __shared__ __attribute__((aligned(16))) short Kl[4096];  // [64 keys][64 d] 8KB
    __shared__ __attribute__((aligned(16))) short Vl[4096];  // [64 d][64 keys] 8KB
    const int lane = threadIdx.x & 63;
    const int wv = threadIdx.x >> 6;          // 0..3
    const int l31 = lane & 31;
    const int hi = lane >> 5;                 // 0/1
    const int id = blockIdx.x;
    const int xcd = id & 7;
    const int r_ = id >> 3;                   // 0..127
    const int qt = 15 - (r_ >> 3);            // 15..0 heavy-first
    const int bh = xcd * 8 + (r_ & 7);
    const int bb = bh >> 4, hh = bh & 15;
    const short* Qh = Qb + (size_t)bb * (S_ * E_) + hh * 64;
    const short* Kh = Kb + (size_t)bb * (S_ * E_) + hh * 64;
    const short* Vh = Vt + (size_t)bh * (D_ * S_);
    const float CEXP = 0.18033688011112042f;  // (1/8)*log2(e)

    const int rstage = wv * 8 + (lane >> 3);                      // 0..31
    const int cstage = (((lane & 7) ^ ((lane >> 3) & 7)) << 4);   // inverse swizzle

    const int q0w = qt * 128 + wv * 32;
    const int q = q0w + l31;

    bf16x8 qf[4];
#pragma unroll
    for (int c = 0; c < 4; ++c)
        qf[c] = *(const bf16x8*)&Qh[(size_t)q * E_ + c * 16 + hi * 8];

    f32x16 acc[2];
#pragma unroll
    for (int d = 0; d < 2; ++d)
#pragma unroll
        for (int r = 0; r < 16; ++r) acc[d][r] = 0.f;
    float m = -3e38f, mC = 0.f, l = 0.f;

    const int nw = (q0w + 95) >> 6;
    const int nt = (qt * 128 + 191) >> 6;

    for (int it = 0; it < nt; ++it) {
        const int kt0 = it * 64;
#pragma unroll
        for (int half = 0; half < 2; ++half) {
            const char* gk = (const char*)(Kh + (size_t)(kt0 + half * 32 + rstage) * E_) + cstage;
            __builtin_amdgcn_global_load_lds(gas(gk), las((char*)Kl + half * 4096 + wv * 1024), 16, 0, 0);
            const char* gv = (const char*)Vh + (size_t)(half * 32 + rstage) * (S_ * 2) + (size_t)kt0 * 2 + cstage;
            __builtin_amdgcn_global_load_lds(gas(gv), las((char*)Vl + half * 4096 + wv * 1024), 16, 0, 0);
        }
        __syncthreads();
        if (it < nw) {
            f32x16 sc0, sc1;
#pragma unroll
            for (int r = 0; r < 16; ++r) { sc0[r] = 0.f; sc1[r] = 0.f; }
#pragma unroll
            for (int c = 0; c < 4; ++c) {
                const int r0 = l31, r1 = 32 + l31;
                bf16x8 kf0 = *(const bf16x8*)((const char*)Kl + r0 * 128 +
                                              ((c * 32 + hi * 16) ^ ((r0 & 7) << 4)));
                bf16x8 kf1 = *(const bf16x8*)((const char*)Kl + r1 * 128 +
                                              ((c * 32 + hi * 16) ^ ((r1 & 7) << 4)));
                sc0 = __builtin_amdgcn_mfma_f32_32x32x16_bf16(kf0, qf[c], sc0, 0, 0, 0);
                sc1 = __builtin_amdgcn_mfma_f32_32x32x16_bf16(kf1, qf[c], sc1, 0, 0, 0);
            }
            if (kt0 + 63 > q0w) {
                const int kb = kt0 + 4 * hi;
#pragma unroll
                for (int r = 0; r < 16; ++r) {
                    int key = kb + (r & 3) + 8 * (r >> 2);
                    sc0[r] = (key > q) ? -3e38f : sc0[r];
                    sc1[r] = (key + 32 > q) ? -3e38f : sc1[r];
                }
            }
            float tmx[8];
#pragma unroll
            for (int r = 0; r < 8; ++r)
                tmx[r] = fmaxf(fmaxf(sc0[2 * r], sc0[2 * r + 1]),
                               fmaxf(sc1[2 * r], sc1[2 * r + 1]));
            float tm = fmaxf(fmaxf(fmaxf(tmx[0], tmx[1]), fmaxf(tmx[2], tmx[3])),
                             fmaxf(fmaxf(tmx[4], tmx[5]), fmaxf(tmx[6], tmx[7])));
            tm = fmaxf(tm, __shfl_xor(tm, 32, 64));
            bool need = (tm > m + 16.0f);
            if (__ballot((int)need) != 0ull) {
                float mn = fmaxf(m, tm);
                float sf = exp2a((m - mn) * CEXP);
                m = mn; mC = mn * CEXP;
                l *= sf;
#pragma unroll
                for (int d = 0; d < 2; ++d)
#pragma unroll
                    for (int r = 0; r < 16; ++r) acc[d][r] *= sf;
            }
#pragma unroll
            for (int r = 0; r < 16; ++r) {
                sc0[r] = exp2a(fmaf(sc0[r], CEXP, -mC));
                sc1[r] = exp2a(fmaf(sc1[r], CEXP, -mC));
            }
            float s0 = 0.f, s1 = 0.f;
#pragma unroll
            for (int r = 0; r < 8; ++r) {
                s0 += sc0[2 * r] + sc0[2 * r + 1];
                s1 += sc1[2 * r] + sc1[2 * r + 1];
            }
            float ls = s0 + s1;
            ls += __shfl_xor(ls, 32, 64);
            l += ls;
            const bool lo = (hi == 0);
            bf16x8 pf[4];
#pragma unroll
            for (int s = 0; s < 2; ++s) {
                const f32x16& p = s ? sc1 : sc0;
                unsigned W0 = cvtpk(p[0], p[1]),   W1 = cvtpk(p[2], p[3]);
                unsigned W2 = cvtpk(p[4], p[5]),   W3 = cvtpk(p[6], p[7]);
                unsigned W4 = cvtpk(p[8], p[9]),   W5 = cvtpk(p[10], p[11]);
                unsigned W6 = cvtpk(p[12], p[13]), W7 = cvtpk(p[14], p[15]);
                unsigned xW0 = __shfl_xor(W0, 32, 64), xW1 = __shfl_xor(W1, 32, 64);
                unsigned xW2 = __shfl_xor(W2, 32, 64), xW3 = __shfl_xor(W3, 32, 64);
                unsigned xW4 = __shfl_xor(W4, 32, 64), xW5 = __shfl_xor(W5, 32, 64);
                unsigned xW6 = __shfl_xor(W6, 32, 64), xW7 = __shfl_xor(W7, 32, 64);
                uint4v u1, u2;
                u1[0] = lo ? W0 : xW2;  u1[1] = lo ? W1 : xW3;
                u1[2] = lo ? xW0 : W2;  u1[3] = lo ? xW1 : W3;
                u2[0] = lo ? W4 : xW6;  u2[1] = lo ? W5 : xW7;
                u2[2] = lo ? xW4 : W6;  u2[3] = lo ? xW5 : W7;
                pf[s * 2] = __builtin_bit_cast(bf16x8, u1);
                pf[s * 2 + 1] = __builtin_bit_cast(bf16x8, u2);
            }
#pragma unroll
            for (int db = 0; db < 2; ++db) {
                const int row = db * 32 + l31;
                const int rsw = (row & 7) << 4;
                const char* vrow = (const char*)Vl + row * 128;
                bf16x8 v0 = *(const bf16x8*)(vrow + ((hi * 16) ^ rsw));
                bf16x8 v1 = *(const bf16x8*)(vrow + ((32 + hi * 16) ^ rsw));
                bf16x8 v2 = *(const bf16x8*)(vrow + ((64 + hi * 16) ^ rsw));
                bf16x8 v3 = *(const bf16x8*)(vrow + ((96 + hi * 16) ^ rsw));
                acc[db] = __builtin_amdgcn_mfma_f32_32x32x16_bf16(v0, pf[0], acc[db], 0, 0, 0);
                acc[db] = __builtin_amdgcn_mfma_f32_32x32x16_bf16(v1, pf[1], acc[db], 0, 0, 0);
                acc[db] = __builtin_amdgcn_mfma_f32_32x32x16_bf16(v2, pf[2], acc[db], 0, 0, 0);
                acc[db] = __builtin_amdgcn_mfma_f32_32x32x16_bf16(v3, pf[3], acc[db], 0, 0, 0);
            }
        }
        __syncthreads();
    }

    float rl = __builtin_amdgcn_rcpf(l);
    short* orow = Ob + ((size_t)(bb * S_ + q)) * E_ + hh * 64;
#pragma unroll
    for (int db = 0; db < 2; ++db)
#pragma unroll
        for (int rb = 0; rb < 4; ++rb) {
            uint2v pk;
            pk[0] = cvtpk(acc[db][rb * 4 + 0] * rl, acc[db][rb * 4 + 1] * rl);
            pk[1] = cvtpk(acc[db][rb * 4 + 2] * rl, acc[db][rb * 4 + 3] * rl);
            *(uint2v*)&orow[db * 32 + rb * 8 + hi * 4] = pk;
        }
}

extern "C" void kernel_launch(void* const* d_in, const int* in_sizes, int n_in,
                              void* d_out, int out_size, void* d_ws, size_t ws_size,
                              hipStream_t stream) {
    const float* x      = (const float*)d_in[0];
    const float* w_attn = (const float*)d_in[1];
    const float* b_attn = (const float*)d_in[2];
    const float* w_out  = (const float*)d_in[3];
    const float* b_out  = (const float*)d_in[4];
    float* out = (float*)d_out;

    char* ws = (char*)d_ws;
    short* Xbf  = (short*)(ws);                       // 16 MB (reused as attn output)
    short* Wat  = (short*)(ws + (16ull << 20));       // 6 MB  [3072][1024]
    short* Wot  = (short*)(ws + (22ull << 20));       // 2 MB  [1024][1024]
    short* Qb   = (short*)(ws + (24ull << 20));       // 16 MB flat [8192][1024]
    short* Kb   = (short*)(ws + (40ull << 20));       // 16 MB flat [8192][1024]
    short* Vt   = (short*)(ws + (56ull << 20));       // 16 MB [B,H,D,S]
    short* Obuf = Xbf;

    convert_f32_bf16<<<2048, 256, 0, stream>>>(x, Xbf, M_ * E_);
    transpose_convert<<<dim3(N1_ / 32, E_ / 32), dim3(32, 8), 0, stream>>>(w_attn, Wat, E_, N1_);
    transpose_convert<<<dim3(E_ / 32, E_ / 32), dim3(32, 8), 0, stream>>>(w_out, Wot, E_, E_);

    gemm_qkv<<<512, 512, 0, stream>>>(Xbf, Wat, b_attn, Qb, Kb, Vt);

    attn_kernel<<<1024, 256, 0, stream>>>(Qb, Kb, Vt, Obuf);

    gemm_out8<<<256, 512, 0, stream>>>(Obuf, Wot, b_out, out);
}

// Round 14
// 167.590 us; speedup vs baseline: 1.1474x; 1.0476x over previous
//
#include <hip/hip_runtime.h>

typedef short bf16x8 __attribute__((ext_vector_type(8)));
typedef float f32x4 __attribute__((ext_vector_type(4)));
typedef float f32x16 __attribute__((ext_vector_type(16)));
typedef float float4v __attribute__((ext_vector_type(4)));
typedef short short4v __attribute__((ext_vector_type(4)));
typedef unsigned uint2v __attribute__((ext_vector_type(2)));
typedef unsigned uint4v __attribute__((ext_vector_type(4)));

#define B_ 4
#define S_ 2048
#define E_ 1024
#define H_ 16
#define D_ 64
#define M_ (B_*S_)      // 8192
#define N1_ (3*E_)      // 3072

__device__ inline short f2bs(float f) {
    unsigned u = __builtin_bit_cast(unsigned, f);
    unsigned r = u + 0x7fffu + ((u >> 16) & 1u);
    return (short)(r >> 16);
}
__device__ inline float exp2a(float x) {
    float r; asm("v_exp_f32 %0, %1" : "=v"(r) : "v"(x)); return r;
}
__device__ inline unsigned cvtpk(float a, float b) {
    unsigned r; asm("v_cvt_pk_bf16_f32 %0, %1, %2" : "=v"(r) : "v"(a), "v"(b)); return r;
}

__device__ inline const __attribute__((address_space(1))) void* gas(const void* p) {
    return (const __attribute__((address_space(1))) void*)p;
}
__device__ inline __attribute__((address_space(3))) void* las(void* p) {
    return (__attribute__((address_space(3))) void*)p;
}

// ---------------- elementwise fp32 -> bf16 ----------------
__global__ void convert_f32_bf16(const float* __restrict__ in, short* __restrict__ out, int n) {
    int tid = blockIdx.x * blockDim.x + threadIdx.x;
    int stride = gridDim.x * blockDim.x;
    for (int i = tid * 4; i < n; i += stride * 4) {
        float4v v = *(const float4v*)&in[i];
        short4v o;
        o[0] = f2bs(v[0]); o[1] = f2bs(v[1]); o[2] = f2bs(v[2]); o[3] = f2bs(v[3]);
        *(short4v*)&out[i] = o;
    }
}

// ---------------- tiled transpose + convert ----------------
__global__ void transpose_convert(const float* __restrict__ in, short* __restrict__ out,
                                  int rows, int cols) {
    __shared__ float t[32][33];
    int bx = blockIdx.x * 32;
    int by = blockIdx.y * 32;
    int tx = threadIdx.x, ty = threadIdx.y;  // (32, 8)
#pragma unroll
    for (int i = 0; i < 4; ++i)
        t[ty + i * 8][tx] = in[(size_t)(by + ty + i * 8) * cols + bx + tx];
    __syncthreads();
#pragma unroll
    for (int i = 0; i < 4; ++i)
        out[(size_t)(bx + ty + i * 8) * rows + by + tx] = f2bs(t[tx][ty + i * 8]);
}

#define VMW(n) asm volatile("s_waitcnt vmcnt(" #n ")" ::: "memory")
#define NOP_ ((void)0)

// ================= 128x192 GEMM (QKV), 256 thr, 80KB LDS -> 2 blocks/CU =================
// 4 waves (2 wr x 2 wc): per-wave 64 rows x 96 cols, acc[4][6]. BK=64.
// A staged m-frag-major: call Q = the 16-row frags phase Q reads (both wr halves).
// Stagger: P0 stageB(x6) | P1 stageA(x4) + VMW(8) | P3 VMW(2). Invariant: A2,A3(t+1)
// in flight across tile boundary; 2nd resident block covers drains.
#define QKV_MFMA(Q) \
    _Pragma("unroll") for (int nf = 0; nf < 6; ++nf) { \
        acc[(Q)][nf] = __builtin_amdgcn_mfma_f32_16x16x32_bf16(af[0], bfrag[nf][0], acc[(Q)][nf], 0, 0, 0); \
        acc[(Q)][nf] = __builtin_amdgcn_mfma_f32_16x16x32_bf16(af[1], bfrag[nf][1], acc[(Q)][nf], 0, 0, 0); \
    }

#define QKV_PHASE(Q, STAGE_STMT, WAITV) do { \
    bf16x8 af[2]; \
    const char* lAq = lA + (Q) * 4096; \
    _Pragma("unroll") for (int ks = 0; ks < 2; ++ks) \
        af[ks] = *(const bf16x8*)(lAq + li * 128 + ((ks * 64 + g * 16) ^ ((li & 7) << 4))); \
    STAGE_STMT; \
    __builtin_amdgcn_s_barrier(); \
    asm volatile("s_waitcnt lgkmcnt(0)" ::: "memory"); \
    __builtin_amdgcn_sched_barrier(0); \
    __builtin_amdgcn_s_setprio(1); \
    QKV_MFMA(Q); \
    __builtin_amdgcn_s_setprio(0); \
    WAITV; \
    __builtin_amdgcn_s_barrier(); \
} while (0)

__global__ __launch_bounds__(256, 2) void gemm_qkv(
    const short* __restrict__ A, const short* __restrict__ Bt,
    const float* __restrict__ bias,
    short* __restrict__ Qb, short* __restrict__ Kb, short* __restrict__ Vt) {
    __shared__ __attribute__((aligned(16))) short ldsA[2][8192];   // [buf][4 calls][2 wr][16r][64k] 16KB
    __shared__ __attribute__((aligned(16))) short ldsB[2][12288];  // [buf][192r][64k] 24KB  (total 80KB)
    const int tid = threadIdx.x;
    const int lane = tid & 63;
    const int wid = tid >> 6;         // 0..3
    const int li = lane & 15, g = lane >> 4;
    const int wr = wid >> 1, wc = wid & 1;
    const int Kdim = E_;
    const int NT = Kdim >> 6;  // 16

    // bijective XCD swizzle: nwg=1024, 1024/8=128
    const int id = blockIdx.x;
    const int swz = (id & 7) * 128 + (id >> 3);
    const int bx = swz & 15, by = swz >> 4;      // 16 col-tiles, 64 row-tiles
    const int row0 = by * 128, col0 = bx * 192;

    const int lr8 = lane >> 3;                                // 0..7
    const int cstage = (((lane & 7) ^ (lr8 & 7)) << 4);       // inverse swizzle (row&7 = lr8)

    // A call Q: lanes cover frag rows {Q*16 + r16} for half wr' = wid>>1,
    // r16 = (wid&1)*8 + lr8. Global row = wr'*64 + Q*16 + r16.
    auto stageA = [&](int buf, int kt) {
#pragma unroll
        for (int Q = 0; Q < 4; ++Q) {
            int grow = (wid >> 1) * 64 + Q * 16 + (wid & 1) * 8 + lr8;
            const char* src = (const char*)A +
                ((size_t)(row0 + grow) * Kdim + kt * 64) * 2 + cstage;
            char* dst = (char*)&ldsA[buf][0] + Q * 4096 + wid * 1024;
            __builtin_amdgcn_global_load_lds(gas(src), las(dst), 16, 0, 0);
        }
    };
    auto stageB = [&](int buf, int kt) {
#pragma unroll
        for (int i = 0; i < 6; ++i) {
            int grow = i * 32 + wid * 8 + lr8;
            const char* src = (const char*)Bt +
                ((size_t)(col0 + grow) * Kdim + kt * 64) * 2 + cstage;
            char* dst = (char*)&ldsB[buf][0] + i * 4096 + wid * 1024;
            __builtin_amdgcn_global_load_lds(gas(src), las(dst), 16, 0, 0);
        }
    };

    f32x4 acc[4][6];
#pragma unroll
    for (int m = 0; m < 4; ++m)
#pragma unroll
        for (int n = 0; n < 6; ++n) acc[m][n] = (f32x4){0.f, 0.f, 0.f, 0.f};

    stageB(0, 0);
    stageA(0, 0);
    asm volatile("s_waitcnt vmcnt(0)" ::: "memory");
    __syncthreads();

    for (int t = 0; t < NT; ++t) {
        const int cur = t & 1;
        const int nb = cur ^ 1;
        const int tn = t + 1;
        const bool st = (tn < NT);
        const char* lA = (const char*)&ldsA[cur][0] + wr * 2048;  // half within each call
        const char* lB = (const char*)&ldsB[cur][0];

        bf16x8 bfrag[6][2];
#pragma unroll
        for (int nf = 0; nf < 6; ++nf)
#pragma unroll
            for (int ks = 0; ks < 2; ++ks) {
                int r = wc * 96 + nf * 16 + li;
                bfrag[nf][ks] = *(const bf16x8*)(lB + r * 128 + ((ks * 64 + g * 16) ^ ((r & 7) << 4)));
            }
        if (st) {
            QKV_PHASE(0, stageB(nb, tn), NOP_);
            QKV_PHASE(1, stageA(nb, tn), VMW(8));
            QKV_PHASE(2, NOP_, NOP_);
            QKV_PHASE(3, NOP_, VMW(2));
        } else {
            QKV_PHASE(0, NOP_, NOP_);
            QKV_PHASE(1, NOP_, VMW(0));
            QKV_PHASE(2, NOP_, NOP_);
            QKV_PHASE(3, NOP_, NOP_);
        }
    }

    // ---- epilogue (C layout: col = lane&15, row = (lane>>4)*4 + j) ----
#pragma unroll
    for (int nf = 0; nf < 6; ++nf) {
        int ncolg = col0 + wc * 96 + nf * 16 + li;
        float bv = bias[ncolg];
        int part = ncolg >> 10;
        int rem = ncolg & 1023;
        if (part < 2) {
            short* Dst = (part == 0) ? Qb : Kb;
#pragma unroll
            for (int mi = 0; mi < 4; ++mi) {
                int rbase = row0 + wr * 64 + mi * 16 + 4 * g;
#pragma unroll
                for (int j = 0; j < 4; ++j)
                    Dst[(size_t)(rbase + j) * E_ + rem] = f2bs(acc[mi][nf][j] + bv);
            }
        } else {
            int h = rem >> 6, d = rem & 63;
#pragma unroll
            for (int mi = 0; mi < 4; ++mi) {
                int s0 = row0 + wr * 64 + mi * 16 + 4 * g;
                int bb2 = s0 >> 11;
                int ss = s0 & 2047;
                uint2v p;
                p[0] = cvtpk(acc[mi][nf][0] + bv, acc[mi][nf][1] + bv);
                p[1] = cvtpk(acc[mi][nf][2] + bv, acc[mi][nf][3] + bv);
                *(uint2v*)&Vt[((size_t)(bb2 * H_ + h) * D_ + d) * S_ + ss] = p;
            }
        }
    }
}

// ================= 256x128 8-phase GEMM (out-proj), grid 256 = 1x256 exact =================
#define MFMA8(Q) \
    _Pragma("unroll") for (int mf = 0; mf < 2; ++mf) \
    _Pragma("unroll") for (int nf = 0; nf < 2; ++nf) { \
        acc[(Q)*2+mf][nf] = __builtin_amdgcn_mfma_f32_16x16x32_bf16(af[mf][0], bfrag[nf][0], acc[(Q)*2+mf][nf], 0, 0, 0); \
        acc[(Q)*2+mf][nf] = __builtin_amdgcn_mfma_f32_16x16x32_bf16(af[mf][1], bfrag[nf][1], acc[(Q)*2+mf][nf], 0, 0, 0); \
    }

#define PHASE8(Q, STAGE_STMT, WAITV) do { \
    bf16x8 af[2][2]; \
    _Pragma("unroll") for (int mf = 0; mf < 2; ++mf) \
    _Pragma("unroll") for (int ks = 0; ks < 2; ++ks) { \
        int r = (Q)*32 + mf*16 + li; \
        af[mf][ks] = *(const bf16x8*)(lA + r*128 + ((ks*64 + g*16) ^ ((r & 7) << 4))); \
    } \
    STAGE_STMT; \
    __builtin_amdgcn_s_barrier(); \
    asm volatile("s_waitcnt lgkmcnt(0)" ::: "memory"); \
    __builtin_amdgcn_sched_barrier(0); \
    __builtin_amdgcn_s_setprio(1); \
    MFMA8(Q); \
    __builtin_amdgcn_s_setprio(0); \
    WAITV; \
    __builtin_amdgcn_s_barrier(); \
} while (0)

__global__ __launch_bounds__(512, 2) void gemm_out8(
    const short* __restrict__ A, const short* __restrict__ Bt,
    const float* __restrict__ bias, float* __restrict__ Cf) {
    __shared__ __attribute__((aligned(16))) short ldsA[2][2][2][4096];  // [buf][half][seg][64x64]
    __shared__ __attribute__((aligned(16))) short ldsB[2][8192];        // [buf][128x64]
    const int tid = threadIdx.x;
    const int lane = tid & 63;
    const int wid = tid >> 6;
    const int li = lane & 15, g = lane >> 4;
    const int wr = wid >> 2, wc = wid & 3;
    const int Kdim = E_;
    const int NT = Kdim >> 6;

    const int id = blockIdx.x;
    const int swz = (id & 7) * 32 + (id >> 3);
    const int bx = swz & 7, by = swz >> 3;
    const int row0 = by * 256, col0 = bx * 128;

    const int rstage = wid * 8 + (lane >> 3);
    const int cstage = (((lane & 7) ^ ((lane >> 3) & 7)) << 4);

    auto stageA = [&](int buf, int kt, int seg) {
#pragma unroll
        for (int h = 0; h < 2; ++h) {
            const char* src = (const char*)A +
                ((size_t)(row0 + h * 128 + seg * 64 + rstage) * Kdim + kt * 64) * 2 + cstage;
            char* dst = (char*)&ldsA[buf][h][seg][0] + wid * 1024;
            __builtin_amdgcn_global_load_lds(gas(src), las(dst), 16, 0, 0);
        }
    };
    auto stageB = [&](int buf, int kt) {
#pragma unroll
        for (int i = 0; i < 2; ++i) {
            const char* src = (const char*)Bt +
                ((size_t)(col0 + i * 64 + rstage) * Kdim + kt * 64) * 2 + cstage;
            char* dst = (char*)&ldsB[buf][0] + i * 8192 + wid * 1024;
            __builtin_amdgcn_global_load_lds(gas(src), las(dst), 16, 0, 0);
        }
    };

    f32x4 acc[8][2];
#pragma unroll
    for (int m = 0; m < 8; ++m)
#pragma unroll
        for (int n = 0; n < 2; ++n) acc[m][n] = (f32x4){0.f, 0.f, 0.f, 0.f};

    stageB(0, 0);
    stageA(0, 0, 0);
    stageA(0, 0, 1);
    asm volatile("s_waitcnt vmcnt(0)" ::: "memory");
    __syncthreads();

    for (int t = 0; t < NT; ++t) {
        const int cur = t & 1;
        const int nb = cur ^ 1;
        const int tn = t + 1;
        const bool st = (tn < NT);
        const char* lA = (const char*)&ldsA[cur][wr][0][0];
        const char* lB = (const char*)&ldsB[cur][0];

        bf16x8 bfrag[2][2];
#pragma unroll
        for (int nf = 0; nf < 2; ++nf)
#pragma unroll
            for (int ks = 0; ks < 2; ++ks) {
                int r = wc * 32 + nf * 16 + li;
                bfrag[nf][ks] = *(const bf16x8*)(lB + r * 128 + ((ks * 64 + g * 16) ^ ((r & 7) << 4)));
            }
        if (st) {
            PHASE8(0, stageB(nb, tn), NOP_);
            PHASE8(1, stageA(nb, tn, 0), VMW(4));
            PHASE8(2, stageA(nb, tn, 1), NOP_);
            PHASE8(3, NOP_, VMW(2));
        } else {
            PHASE8(0, NOP_, NOP_);
            PHASE8(1, NOP_, VMW(0));
            PHASE8(2, NOP_, NOP_);
            PHASE8(3, NOP_, NOP_);
        }
    }

#pragma unroll
    for (int nf = 0; nf < 2; ++nf) {
        int ncol = col0 + wc * 32 + nf * 16 + li;
        float bv = bias[ncol];
#pragma unroll
        for (int mi = 0; mi < 8; ++mi) {
            int rbase = row0 + wr * 128 + mi * 16 + 4 * g;
#pragma unroll
            for (int j = 0; j < 4; ++j)
                Cf[(size_t)(rbase + j) * E_ + ncol] = acc[mi][nf][j] + bv;
        }
    }
}

// ---------------- causal flash attention v7b (R10/R12 verified) ----------------
__global__ __launch_bounds__(256, 4) void attn_kernel(
    const short* __restrict__ Qb, const short* __restrict__ Kb,
    const short* __restrict__ Vt, short* __restrict__ Ob) {
    __shared__ __attribute__((aligned(16))) short Kl[4096];  // [64 keys][64 d] 8KB
    __shared__ __attribute__((aligned(16))) short Vl[4096];  // [64 d][64 keys] 8KB
    const int lane = threadIdx.x & 63;
    const int wv = threadIdx.x >> 6;
    const int l31 = lane & 31;
    const int hi = lane >> 5;
    const int id = blockIdx.x;
    const int xcd = id & 7;
    const int r_ = id >> 3;
    const int qt = 15 - (r_ >> 3);
    const int bh = xcd * 8 + (r_ & 7);
    const int bb = bh >> 4, hh = bh & 15;
    const short* Qh = Qb + (size_t)bb * (S_ * E_) + hh * 64;
    const short* Kh = Kb + (size_t)bb * (S_ * E_) + hh * 64;
    const short* Vh = Vt + (size_t)bh * (D_ * S_);
    const float CEXP = 0.18033688011112042f;

    const int rstage = wv * 8 + (lane >> 3);
    const int cstage = (((lane & 7) ^ ((lane >> 3) & 7)) << 4);

    const int q0w = qt * 128 + wv * 32;
    const int q = q0w + l31;

    bf16x8 qf[4];
#pragma unroll
    for (int c = 0; c < 4; ++c)
        qf[c] = *(const bf16x8*)&Qh[(size_t)q * E_ + c * 16 + hi * 8];

    f32x16 acc[2];
#pragma unroll
    for (int d = 0; d < 2; ++d)
#pragma unroll
        for (int r = 0; r < 16; ++r) acc[d][r] = 0.f;
    float m = -3e38f, mC = 0.f, l = 0.f;

    const int nw = (q0w + 95) >> 6;
    const int nt = (qt * 128 + 191) >> 6;

    for (int it = 0; it < nt; ++it) {
        const int kt0 = it * 64;
#pragma unroll
        for (int half = 0; half < 2; ++half) {
            const char* gk = (const char*)(Kh + (size_t)(kt0 + half * 32 + rstage) * E_) + cstage;
            __builtin_amdgcn_global_load_lds(gas(gk), las((char*)Kl + half * 4096 + wv * 1024), 16, 0, 0);
            const char* gv = (const char*)Vh + (size_t)(half * 32 + rstage) * (S_ * 2) + (size_t)kt0 * 2 + cstage;
            __builtin_amdgcn_global_load_lds(gas(gv), las((char*)Vl + half * 4096 + wv * 1024), 16, 0, 0);
        }
        __syncthreads();
        if (it < nw) {
            f32x16 sc0, sc1;
#pragma unroll
            for (int r = 0; r < 16; ++r) { sc0[r] = 0.f; sc1[r] = 0.f; }
#pragma unroll
            for (int c = 0; c < 4; ++c) {
                const int r0 = l31, r1 = 32 + l31;
                bf16x8 kf0 = *(const bf16x8*)((const char*)Kl + r0 * 128 +
                                              ((c * 32 + hi * 16) ^ ((r0 & 7) << 4)));
                bf16x8 kf1 = *(const bf16x8*)((const char*)Kl + r1 * 128 +
                                              ((c * 32 + hi * 16) ^ ((r1 & 7) << 4)));
                sc0 = __builtin_amdgcn_mfma_f32_32x32x16_bf16(kf0, qf[c], sc0, 0, 0, 0);
                sc1 = __builtin_amdgcn_mfma_f32_32x32x16_bf16(kf1, qf[c], sc1, 0, 0, 0);
            }
            if (kt0 + 63 > q0w) {
                const int kb = kt0 + 4 * hi;
#pragma unroll
                for (int r = 0; r < 16; ++r) {
                    int key = kb + (r & 3) + 8 * (r >> 2);
                    sc0[r] = (key > q) ? -3e38f : sc0[r];
                    sc1[r] = (key + 32 > q) ? -3e38f : sc1[r];
                }
            }
            float tmx[8];
#pragma unroll
            for (int r = 0; r < 8; ++r)
                tmx[r] = fmaxf(fmaxf(sc0[2 * r], sc0[2 * r + 1]),
                               fmaxf(sc1[2 * r], sc1[2 * r + 1]));
            float tm = fmaxf(fmaxf(fmaxf(tmx[0], tmx[1]), fmaxf(tmx[2], tmx[3])),
                             fmaxf(fmaxf(tmx[4], tmx[5]), fmaxf(tmx[6], tmx[7])));
            tm = fmaxf(tm, __shfl_xor(tm, 32, 64));
            bool need = (tm > m + 16.0f);
            if (__ballot((int)need) != 0ull) {
                float mn = fmaxf(m, tm);
                float sf = exp2a((m - mn) * CEXP);
                m = mn; mC = mn * CEXP;
                l *= sf;
#pragma unroll
                for (int d = 0; d < 2; ++d)
#pragma unroll
                    for (int r = 0; r < 16; ++r) acc[d][r] *= sf;
            }
#pragma unroll
            for (int r = 0; r < 16; ++r) {
                sc0[r] = exp2a(fmaf(sc0[r], CEXP, -mC));
                sc1[r] = exp2a(fmaf(sc1[r], CEXP, -mC));
            }
            float s0 = 0.f, s1 = 0.f;
#pragma unroll
            for (int r = 0; r < 8; ++r) {
                s0 += sc0[2 * r] + sc0[2 * r + 1];
                s1 += sc1[2 * r] + sc1[2 * r + 1];
            }
            float ls = s0 + s1;
            ls += __shfl_xor(ls, 32, 64);
            l += ls;
            const bool lo = (hi == 0);
            bf16x8 pf[4];
#pragma unroll
            for (int s = 0; s < 2; ++s) {
                const f32x16& p = s ? sc1 : sc0;
                unsigned W0 = cvtpk(p[0], p[1]),   W1 = cvtpk(p[2], p[3]);
                unsigned W2 = cvtpk(p[4], p[5]),   W3 = cvtpk(p[6], p[7]);
                unsigned W4 = cvtpk(p[8], p[9]),   W5 = cvtpk(p[10], p[11]);
                unsigned W6 = cvtpk(p[12], p[13]), W7 = cvtpk(p[14], p[15]);
                unsigned xW0 = __shfl_xor(W0, 32, 64), xW1 = __shfl_xor(W1, 32, 64);
                unsigned xW2 = __shfl_xor(W2, 32, 64), xW3 = __shfl_xor(W3, 32, 64);
                unsigned xW4 = __shfl_xor(W4, 32, 64), xW5 = __shfl_xor(W5, 32, 64);
                unsigned xW6 = __shfl_xor(W6, 32, 64), xW7 = __shfl_xor(W7, 32, 64);
                uint4v u1, u2;
                u1[0] = lo ? W0 : xW2;  u1[1] = lo ? W1 : xW3;
                u1[2] = lo ? xW0 : W2;  u1[3] = lo ? xW1 : W3;
                u2[0] = lo ? W4 : xW6;  u2[1] = lo ? W5 : xW7;
                u2[2] = lo ? xW4 : W6;  u2[3] = lo ? xW5 : W7;
                pf[s * 2] = __builtin_bit_cast(bf16x8, u1);
                pf[s * 2 + 1] = __builtin_bit_cast(bf16x8, u2);
            }
#pragma unroll
            for (int db = 0; db < 2; ++db) {
                const int row = db * 32 + l31;
                const int rsw = (row & 7) << 4;
                const char* vrow = (const char*)Vl + row * 128;
                bf16x8 v0 = *(const bf16x8*)(vrow + ((hi * 16) ^ rsw));
                bf16x8 v1 = *(const bf16x8*)(vrow + ((32 + hi * 16) ^ rsw));
                bf16x8 v2 = *(const bf16x8*)(vrow + ((64 + hi * 16) ^ rsw));
                bf16x8 v3 = *(const bf16x8*)(vrow + ((96 + hi * 16) ^ rsw));
                acc[db] = __builtin_amdgcn_mfma_f32_32x32x16_bf16(v0, pf[0], acc[db], 0, 0, 0);
                acc[db] = __builtin_amdgcn_mfma_f32_32x32x16_bf16(v1, pf[1], acc[db], 0, 0, 0);
                acc[db] = __builtin_amdgcn_mfma_f32_32x32x16_bf16(v2, pf[2], acc[db], 0, 0, 0);
                acc[db] = __builtin_amdgcn_mfma_f32_32x32x16_bf16(v3, pf[3], acc[db], 0, 0, 0);
            }
        }
        __syncthreads();
    }

    float rl = __builtin_amdgcn_rcpf(l);
    short* orow = Ob + ((size_t)(bb * S_ + q)) * E_ + hh * 64;
#pragma unroll
    for (int db = 0; db < 2; ++db)
#pragma unroll
        for (int rb = 0; rb < 4; ++rb) {
            uint2v pk;
            pk[0] = cvtpk(acc[db][rb * 4 + 0] * rl, acc[db][rb * 4 + 1] * rl);
            pk[1] = cvtpk(acc[db][rb * 4 + 2] * rl, acc[db][rb * 4 + 3] * rl);
            *(uint2v*)&orow[db * 32 + rb * 8 + hi * 4] = pk;
        }
}

extern "C" void kernel_launch(void* const* d_in, const int* in_sizes, int n_in,
                              void* d_out, int out_size, void* d_ws, size_t ws_size,
                              hipStream_t stream) {
    const float* x      = (const float*)d_in[0];
    const float* w_attn = (const float*)d_in[1];
    const float* b_attn = (const float*)d_in[2];
    const float* w_out  = (const float*)d_in[3];
    const float* b_out  = (const float*)d_in[4];
    float* out = (float*)d_out;

    char* ws = (char*)d_ws;
    short* Xbf  = (short*)(ws);                       // 16 MB (reused as attn output)
    short* Wat  = (short*)(ws + (16ull << 20));       // 6 MB  [3072][1024]
    short* Wot  = (short*)(ws + (22ull << 20));       // 2 MB  [1024][1024]
    short* Qb   = (short*)(ws + (24ull << 20));       // 16 MB flat [8192][1024]
    short* Kb   = (short*)(ws + (40ull << 20));       // 16 MB flat [8192][1024]
    short* Vt   = (short*)(ws + (56ull << 20));       // 16 MB [B,H,D,S]
    short* Obuf = Xbf;

    convert_f32_bf16<<<2048, 256, 0, stream>>>(x, Xbf, M_ * E_);
    transpose_convert<<<dim3(N1_ / 32, E_ / 32), dim3(32, 8), 0, stream>>>(w_attn, Wat, E_, N1_);
    transpose_convert<<<dim3(E_ / 32, E_ / 32), dim3(32, 8), 0, stream>>>(w_out, Wot, E_, E_);

    gemm_qkv<<<1024, 256, 0, stream>>>(Xbf, Wat, b_attn, Qb, Kb, Vt);

    attn_kernel<<<1024, 256, 0, stream>>>(Qb, Kb, Vt, Obuf);

    gemm_out8<<<256, 512, 0, stream>>>(Obuf, Wot, b_out, out);
}

// Round 15
// 162.635 us; speedup vs baseline: 1.1823x; 1.0305x over previous
//
#include <hip/hip_runtime.h>

typedef short bf16x8 __attribute__((ext_vector_type(8)));
typedef float f32x4 __attribute__((ext_vector_type(4)));
typedef float f32x16 __attribute__((ext_vector_type(16)));
typedef float float4v __attribute__((ext_vector_type(4)));
typedef short short4v __attribute__((ext_vector_type(4)));
typedef unsigned uint2v __attribute__((ext_vector_type(2)));
typedef unsigned uint4v __attribute__((ext_vector_type(4)));

#define B_ 4
#define S_ 2048
#define E_ 1024
#define H_ 16
#define D_ 64
#define M_ (B_*S_)      // 8192
#define N1_ (3*E_)      // 3072

__device__ inline short f2bs(float f) {
    unsigned u = __builtin_bit_cast(unsigned, f);
    unsigned r = u + 0x7fffu + ((u >> 16) & 1u);
    return (short)(r >> 16);
}
__device__ inline float exp2a(float x) {
    float r; asm("v_exp_f32 %0, %1" : "=v"(r) : "v"(x)); return r;
}
__device__ inline unsigned cvtpk(float a, float b) {
    unsigned r; asm("v_cvt_pk_bf16_f32 %0, %1, %2" : "=v"(r) : "v"(a), "v"(b)); return r;
}

__device__ inline const __attribute__((address_space(1))) void* gas(const void* p) {
    return (const __attribute__((address_space(1))) void*)p;
}
__device__ inline __attribute__((address_space(3))) void* las(void* p) {
    return (__attribute__((address_space(3))) void*)p;
}

// ---------------- elementwise fp32 -> bf16 ----------------
__global__ void convert_f32_bf16(const float* __restrict__ in, short* __restrict__ out, int n) {
    int tid = blockIdx.x * blockDim.x + threadIdx.x;
    int stride = gridDim.x * blockDim.x;
    for (int i = tid * 4; i < n; i += stride * 4) {
        float4v v = *(const float4v*)&in[i];
        short4v o;
        o[0] = f2bs(v[0]); o[1] = f2bs(v[1]); o[2] = f2bs(v[2]); o[3] = f2bs(v[3]);
        *(short4v*)&out[i] = o;
    }
}

// ---------------- tiled transpose + convert ----------------
__global__ void transpose_convert(const float* __restrict__ in, short* __restrict__ out,
                                  int rows, int cols) {
    __shared__ float t[32][33];
    int bx = blockIdx.x * 32;
    int by = blockIdx.y * 32;
    int tx = threadIdx.x, ty = threadIdx.y;  // (32, 8)
#pragma unroll
    for (int i = 0; i < 4; ++i)
        t[ty + i * 8][tx] = in[(size_t)(by + ty + i * 8) * cols + bx + tx];
    __syncthreads();
#pragma unroll
    for (int i = 0; i < 4; ++i)
        out[(size_t)(bx + ty + i * 8) * rows + by + tx] = f2bs(t[tx][ty + i * 8]);
}

#define VMW(n) asm volatile("s_waitcnt vmcnt(" #n ")" ::: "memory")
#define NOP_ ((void)0)

// ================= 128x192 GEMM (QKV), 256 thr, 80KB LDS -> 2 blocks/CU =================
#define QKV_MFMA(Q) \
    _Pragma("unroll") for (int nf = 0; nf < 6; ++nf) { \
        acc[(Q)][nf] = __builtin_amdgcn_mfma_f32_16x16x32_bf16(af[0], bfrag[nf][0], acc[(Q)][nf], 0, 0, 0); \
        acc[(Q)][nf] = __builtin_amdgcn_mfma_f32_16x16x32_bf16(af[1], bfrag[nf][1], acc[(Q)][nf], 0, 0, 0); \
    }

#define QKV_PHASE(Q, STAGE_STMT, WAITV) do { \
    bf16x8 af[2]; \
    const char* lAq = lA + (Q) * 4096; \
    _Pragma("unroll") for (int ks = 0; ks < 2; ++ks) \
        af[ks] = *(const bf16x8*)(lAq + li * 128 + ((ks * 64 + g * 16) ^ ((li & 7) << 4))); \
    STAGE_STMT; \
    __builtin_amdgcn_s_barrier(); \
    asm volatile("s_waitcnt lgkmcnt(0)" ::: "memory"); \
    __builtin_amdgcn_sched_barrier(0); \
    __builtin_amdgcn_s_setprio(1); \
    QKV_MFMA(Q); \
    __builtin_amdgcn_s_setprio(0); \
    WAITV; \
    __builtin_amdgcn_s_barrier(); \
} while (0)

__global__ __launch_bounds__(256, 2) void gemm_qkv(
    const short* __restrict__ A, const short* __restrict__ Bt,
    const float* __restrict__ bias,
    short* __restrict__ Qb, short* __restrict__ Kb, short* __restrict__ Vt) {
    __shared__ __attribute__((aligned(16))) short ldsA[2][8192];   // [buf][4 calls][2 wr][16r][64k]
    __shared__ __attribute__((aligned(16))) short ldsB[2][12288];  // [buf][192r][64k]
    const int tid = threadIdx.x;
    const int lane = tid & 63;
    const int wid = tid >> 6;
    const int li = lane & 15, g = lane >> 4;
    const int wr = wid >> 1, wc = wid & 1;
    const int Kdim = E_;
    const int NT = Kdim >> 6;  // 16

    const int id = blockIdx.x;
    const int swz = (id & 7) * 128 + (id >> 3);
    const int bx = swz & 15, by = swz >> 4;
    const int row0 = by * 128, col0 = bx * 192;

    const int lr8 = lane >> 3;
    const int cstage = (((lane & 7) ^ (lr8 & 7)) << 4);

    auto stageA = [&](int buf, int kt) {
#pragma unroll
        for (int Q = 0; Q < 4; ++Q) {
            int grow = (wid >> 1) * 64 + Q * 16 + (wid & 1) * 8 + lr8;
            const char* src = (const char*)A +
                ((size_t)(row0 + grow) * Kdim + kt * 64) * 2 + cstage;
            char* dst = (char*)&ldsA[buf][0] + Q * 4096 + wid * 1024;
            __builtin_amdgcn_global_load_lds(gas(src), las(dst), 16, 0, 0);
        }
    };
    auto stageB = [&](int buf, int kt) {
#pragma unroll
        for (int i = 0; i < 6; ++i) {
            int grow = i * 32 + wid * 8 + lr8;
            const char* src = (const char*)Bt +
                ((size_t)(col0 + grow) * Kdim + kt * 64) * 2 + cstage;
            char* dst = (char*)&ldsB[buf][0] + i * 4096 + wid * 1024;
            __builtin_amdgcn_global_load_lds(gas(src), las(dst), 16, 0, 0);
        }
    };

    f32x4 acc[4][6];
#pragma unroll
    for (int m = 0; m < 4; ++m)
#pragma unroll
        for (int n = 0; n < 6; ++n) acc[m][n] = (f32x4){0.f, 0.f, 0.f, 0.f};

    stageB(0, 0);
    stageA(0, 0);
    asm volatile("s_waitcnt vmcnt(0)" ::: "memory");
    __syncthreads();

    for (int t = 0; t < NT; ++t) {
        const int cur = t & 1;
        const int nb = cur ^ 1;
        const int tn = t + 1;
        const bool st = (tn < NT);
        const char* lA = (const char*)&ldsA[cur][0] + wr * 2048;
        const char* lB = (const char*)&ldsB[cur][0];

        bf16x8 bfrag[6][2];
#pragma unroll
        for (int nf = 0; nf < 6; ++nf)
#pragma unroll
            for (int ks = 0; ks < 2; ++ks) {
                int r = wc * 96 + nf * 16 + li;
                bfrag[nf][ks] = *(const bf16x8*)(lB + r * 128 + ((ks * 64 + g * 16) ^ ((r & 7) << 4)));
            }
        if (st) {
            QKV_PHASE(0, stageB(nb, tn), NOP_);
            QKV_PHASE(1, stageA(nb, tn), VMW(8));
            QKV_PHASE(2, NOP_, NOP_);
            QKV_PHASE(3, NOP_, VMW(2));
        } else {
            QKV_PHASE(0, NOP_, NOP_);
            QKV_PHASE(1, NOP_, VMW(0));
            QKV_PHASE(2, NOP_, NOP_);
            QKV_PHASE(3, NOP_, NOP_);
        }
    }

    // ---- epilogue ----
#pragma unroll
    for (int nf = 0; nf < 6; ++nf) {
        int ncolg = col0 + wc * 96 + nf * 16 + li;
        float bv = bias[ncolg];
        int part = ncolg >> 10;
        int rem = ncolg & 1023;
        if (part < 2) {
            short* Dst = (part == 0) ? Qb : Kb;
#pragma unroll
            for (int mi = 0; mi < 4; ++mi) {
                int rbase = row0 + wr * 64 + mi * 16 + 4 * g;
#pragma unroll
                for (int j = 0; j < 4; ++j)
                    Dst[(size_t)(rbase + j) * E_ + rem] = f2bs(acc[mi][nf][j] + bv);
            }
        } else {
            int h = rem >> 6, d = rem & 63;
#pragma unroll
            for (int mi = 0; mi < 4; ++mi) {
                int s0 = row0 + wr * 64 + mi * 16 + 4 * g;
                int bb2 = s0 >> 11;
                int ss = s0 & 2047;
                uint2v p;
                p[0] = cvtpk(acc[mi][nf][0] + bv, acc[mi][nf][1] + bv);
                p[1] = cvtpk(acc[mi][nf][2] + bv, acc[mi][nf][3] + bv);
                *(uint2v*)&Vt[((size_t)(bb2 * H_ + h) * D_ + d) * S_ + ss] = p;
            }
        }
    }
}

// ================= 256x128 8-phase GEMM (out-proj), grid 256 = 1x256 exact =================
#define MFMA8(Q) \
    _Pragma("unroll") for (int mf = 0; mf < 2; ++mf) \
    _Pragma("unroll") for (int nf = 0; nf < 2; ++nf) { \
        acc[(Q)*2+mf][nf] = __builtin_amdgcn_mfma_f32_16x16x32_bf16(af[mf][0], bfrag[nf][0], acc[(Q)*2+mf][nf], 0, 0, 0); \
        acc[(Q)*2+mf][nf] = __builtin_amdgcn_mfma_f32_16x16x32_bf16(af[mf][1], bfrag[nf][1], acc[(Q)*2+mf][nf], 0, 0, 0); \
    }

#define PHASE8(Q, STAGE_STMT, WAITV) do { \
    bf16x8 af[2][2]; \
    _Pragma("unroll") for (int mf = 0; mf < 2; ++mf) \
    _Pragma("unroll") for (int ks = 0; ks < 2; ++ks) { \
        int r = (Q)*32 + mf*16 + li; \
        af[mf][ks] = *(const bf16x8*)(lA + r*128 + ((ks*64 + g*16) ^ ((r & 7) << 4))); \
    } \
    STAGE_STMT; \
    __builtin_amdgcn_s_barrier(); \
    asm volatile("s_waitcnt lgkmcnt(0)" ::: "memory"); \
    __builtin_amdgcn_sched_barrier(0); \
    __builtin_amdgcn_s_setprio(1); \
    MFMA8(Q); \
    __builtin_amdgcn_s_setprio(0); \
    WAITV; \
    __builtin_amdgcn_s_barrier(); \
} while (0)

__global__ __launch_bounds__(512, 2) void gemm_out8(
    const short* __restrict__ A, const short* __restrict__ Bt,
    const float* __restrict__ bias, float* __restrict__ Cf) {
    __shared__ __attribute__((aligned(16))) short ldsA[2][2][2][4096];
    __shared__ __attribute__((aligned(16))) short ldsB[2][8192];
    const int tid = threadIdx.x;
    const int lane = tid & 63;
    const int wid = tid >> 6;
    const int li = lane & 15, g = lane >> 4;
    const int wr = wid >> 2, wc = wid & 3;
    const int Kdim = E_;
    const int NT = Kdim >> 6;

    const int id = blockIdx.x;
    const int swz = (id & 7) * 32 + (id >> 3);
    const int bx = swz & 7, by = swz >> 3;
    const int row0 = by * 256, col0 = bx * 128;

    const int rstage = wid * 8 + (lane >> 3);
    const int cstage = (((lane & 7) ^ ((lane >> 3) & 7)) << 4);

    auto stageA = [&](int buf, int kt, int seg) {
#pragma unroll
        for (int h = 0; h < 2; ++h) {
            const char* src = (const char*)A +
                ((size_t)(row0 + h * 128 + seg * 64 + rstage) * Kdim + kt * 64) * 2 + cstage;
            char* dst = (char*)&ldsA[buf][h][seg][0] + wid * 1024;
            __builtin_amdgcn_global_load_lds(gas(src), las(dst), 16, 0, 0);
        }
    };
    auto stageB = [&](int buf, int kt) {
#pragma unroll
        for (int i = 0; i < 2; ++i) {
            const char* src = (const char*)Bt +
                ((size_t)(col0 + i * 64 + rstage) * Kdim + kt * 64) * 2 + cstage;
            char* dst = (char*)&ldsB[buf][0] + i * 8192 + wid * 1024;
            __builtin_amdgcn_global_load_lds(gas(src), las(dst), 16, 0, 0);
        }
    };

    f32x4 acc[8][2];
#pragma unroll
    for (int m = 0; m < 8; ++m)
#pragma unroll
        for (int n = 0; n < 2; ++n) acc[m][n] = (f32x4){0.f, 0.f, 0.f, 0.f};

    stageB(0, 0);
    stageA(0, 0, 0);
    stageA(0, 0, 1);
    asm volatile("s_waitcnt vmcnt(0)" ::: "memory");
    __syncthreads();

    for (int t = 0; t < NT; ++t) {
        const int cur = t & 1;
        const int nb = cur ^ 1;
        const int tn = t + 1;
        const bool st = (tn < NT);
        const char* lA = (const char*)&ldsA[cur][wr][0][0];
        const char* lB = (const char*)&ldsB[cur][0];

        bf16x8 bfrag[2][2];
#pragma unroll
        for (int nf = 0; nf < 2; ++nf)
#pragma unroll
            for (int ks = 0; ks < 2; ++ks) {
                int r = wc * 32 + nf * 16 + li;
                bfrag[nf][ks] = *(const bf16x8*)(lB + r * 128 + ((ks * 64 + g * 16) ^ ((r & 7) << 4)));
            }
        if (st) {
            PHASE8(0, stageB(nb, tn), NOP_);
            PHASE8(1, stageA(nb, tn, 0), VMW(4));
            PHASE8(2, stageA(nb, tn, 1), NOP_);
            PHASE8(3, NOP_, VMW(2));
        } else {
            PHASE8(0, NOP_, NOP_);
            PHASE8(1, NOP_, VMW(0));
            PHASE8(2, NOP_, NOP_);
            PHASE8(3, NOP_, NOP_);
        }
    }

#pragma unroll
    for (int nf = 0; nf < 2; ++nf) {
        int ncol = col0 + wc * 32 + nf * 16 + li;
        float bv = bias[ncol];
#pragma unroll
        for (int mi = 0; mi < 8; ++mi) {
            int rbase = row0 + wr * 128 + mi * 16 + 4 * g;
#pragma unroll
            for (int j = 0; j < 4; ++j)
                Cf[(size_t)(rbase + j) * E_ + ncol] = acc[mi][nf][j] + bv;
        }
    }
}

// ---------------- causal flash attention v9: group-padded LDS + permlane32_swap ----------------
// Group stride 1040B (=1024+16): bank offset 4 per 8-row group kills the 4-way
// read conflict (row starts were all bank-0). Dest of each global_load_lds call
// is still a linear 1024B span per wave (pad is BETWEEN calls) -> m104-safe.
// P-merge: v_permlane32_swap_b32 (a'={a.lo,b.lo}, b'={a.hi,b.hi}) replaces
// shfl_xor(32)+cndmask pairs bit-identically.
#define GRP 1040
__global__ __launch_bounds__(256, 4) void attn_kernel(
    const short* __restrict__ Qb, const short* __restrict__ Kb,
    const short* __restrict__ Vt, short* __restrict__ Ob) {
    __shared__ __attribute__((aligned(16))) char Kl[8 * GRP];  // [8 grp][8 rows][128B]
    __shared__ __attribute__((aligned(16))) char Vl[8 * GRP];
    const int lane = threadIdx.x & 63;
    const int wv = threadIdx.x >> 6;
    const int l31 = lane & 31;
    const int hi = lane >> 5;
    const int id = blockIdx.x;
    const int xcd = id & 7;
    const int r_ = id >> 3;
    const int qt = 15 - (r_ >> 3);
    const int bh = xcd * 8 + (r_ & 7);
    const int bb = bh >> 4, hh = bh & 15;
    const short* Qh = Qb + (size_t)bb * (S_ * E_) + hh * 64;
    const short* Kh = Kb + (size_t)bb * (S_ * E_) + hh * 64;
    const short* Vh = Vt + (size_t)bh * (D_ * S_);
    const float CEXP = 0.18033688011112042f;

    const int rstage = wv * 8 + (lane >> 3);
    const int cstage = (((lane & 7) ^ ((lane >> 3) & 7)) << 4);

    const int q0w = qt * 128 + wv * 32;
    const int q = q0w + l31;

    bf16x8 qf[4];
#pragma unroll
    for (int c = 0; c < 4; ++c)
        qf[c] = *(const bf16x8*)&Qh[(size_t)q * E_ + c * 16 + hi * 8];

    f32x16 acc[2];
#pragma unroll
    for (int d = 0; d < 2; ++d)
#pragma unroll
        for (int r = 0; r < 16; ++r) acc[d][r] = 0.f;
    float m = -3e38f, mC = 0.f, l = 0.f;

    const int nw = (q0w + 95) >> 6;
    const int nt = (qt * 128 + 191) >> 6;

    // per-lane read geometry (row bases into padded groups)
    const int kg0 = (l31 >> 3) * GRP + (l31 & 7) * 128;          // K rows 0..31
    const int kg1 = ((32 + l31) >> 3) * GRP + (l31 & 7) * 128;   // K rows 32..63
    const int ksw = (l31 & 7) << 4;

    for (int it = 0; it < nt; ++it) {
        const int kt0 = it * 64;
#pragma unroll
        for (int half = 0; half < 2; ++half) {
            const int grp = half * 4 + wv;
            const char* gk = (const char*)(Kh + (size_t)(kt0 + half * 32 + rstage) * E_) + cstage;
            __builtin_amdgcn_global_load_lds(gas(gk), las(Kl + grp * GRP), 16, 0, 0);
            const char* gv = (const char*)Vh + (size_t)(half * 32 + rstage) * (S_ * 2) + (size_t)kt0 * 2 + cstage;
            __builtin_amdgcn_global_load_lds(gas(gv), las(Vl + grp * GRP), 16, 0, 0);
        }
        __syncthreads();
        if (it < nw) {
            f32x16 sc0, sc1;
#pragma unroll
            for (int r = 0; r < 16; ++r) { sc0[r] = 0.f; sc1[r] = 0.f; }
#pragma unroll
            for (int c = 0; c < 4; ++c) {
                bf16x8 kf0 = *(const bf16x8*)(Kl + kg0 + ((c * 32 + hi * 16) ^ ksw));
                bf16x8 kf1 = *(const bf16x8*)(Kl + kg1 + ((c * 32 + hi * 16) ^ ksw));
                sc0 = __builtin_amdgcn_mfma_f32_32x32x16_bf16(kf0, qf[c], sc0, 0, 0, 0);
                sc1 = __builtin_amdgcn_mfma_f32_32x32x16_bf16(kf1, qf[c], sc1, 0, 0, 0);
            }
            if (kt0 + 63 > q0w) {
                const int kb = kt0 + 4 * hi;
#pragma unroll
                for (int r = 0; r < 16; ++r) {
                    int key = kb + (r & 3) + 8 * (r >> 2);
                    sc0[r] = (key > q) ? -3e38f : sc0[r];
                    sc1[r] = (key + 32 > q) ? -3e38f : sc1[r];
                }
            }
            float tmx[8];
#pragma unroll
            for (int r = 0; r < 8; ++r)
                tmx[r] = fmaxf(fmaxf(sc0[2 * r], sc0[2 * r + 1]),
                               fmaxf(sc1[2 * r], sc1[2 * r + 1]));
            float tm = fmaxf(fmaxf(fmaxf(tmx[0], tmx[1]), fmaxf(tmx[2], tmx[3])),
                             fmaxf(fmaxf(tmx[4], tmx[5]), fmaxf(tmx[6], tmx[7])));
            tm = fmaxf(tm, __shfl_xor(tm, 32, 64));
            bool need = (tm > m + 16.0f);
            if (__ballot((int)need) != 0ull) {
                float mn = fmaxf(m, tm);
                float sf = exp2a((m - mn) * CEXP);
                m = mn; mC = mn * CEXP;
                l *= sf;
#pragma unroll
                for (int d = 0; d < 2; ++d)
#pragma unroll
                    for (int r = 0; r < 16; ++r) acc[d][r] *= sf;
            }
#pragma unroll
            for (int r = 0; r < 16; ++r) {
                sc0[r] = exp2a(fmaf(sc0[r], CEXP, -mC));
                sc1[r] = exp2a(fmaf(sc1[r], CEXP, -mC));
            }
            float s0 = 0.f, s1 = 0.f;
#pragma unroll
            for (int r = 0; r < 8; ++r) {
                s0 += sc0[2 * r] + sc0[2 * r + 1];
                s1 += sc1[2 * r] + sc1[2 * r + 1];
            }
            float ls = s0 + s1;
            ls += __shfl_xor(ls, 32, 64);
            l += ls;
            // ---- pack: cvt_pk + permlane32_swap (replaces shfl+cndmask merge) ----
            bf16x8 pf[4];
#pragma unroll
            for (int s = 0; s < 2; ++s) {
                const f32x16& p = s ? sc1 : sc0;
                unsigned a0 = cvtpk(p[0], p[1]),   a1 = cvtpk(p[2], p[3]);
                unsigned b0 = cvtpk(p[4], p[5]),   b1 = cvtpk(p[6], p[7]);
                unsigned a2 = cvtpk(p[8], p[9]),   a3 = cvtpk(p[10], p[11]);
                unsigned b2 = cvtpk(p[12], p[13]), b3 = cvtpk(p[14], p[15]);
                asm volatile("v_permlane32_swap_b32 %0, %1" : "+v"(a0), "+v"(b0));
                asm volatile("v_permlane32_swap_b32 %0, %1" : "+v"(a1), "+v"(b1));
                asm volatile("v_permlane32_swap_b32 %0, %1" : "+v"(a2), "+v"(b2));
                asm volatile("v_permlane32_swap_b32 %0, %1" : "+v"(a3), "+v"(b3));
                uint4v u1, u2;
                u1[0] = a0; u1[1] = a1; u1[2] = b0; u1[3] = b1;
                u2[0] = a2; u2[1] = a3; u2[2] = b2; u2[3] = b3;
                pf[s * 2] = __builtin_bit_cast(bf16x8, u1);
                pf[s * 2 + 1] = __builtin_bit_cast(bf16x8, u2);
            }
#pragma unroll
            for (int db = 0; db < 2; ++db) {
                const int row = db * 32 + l31;
                const int rsw = (row & 7) << 4;
                const char* vrow = Vl + (row >> 3) * GRP + (row & 7) * 128;
                bf16x8 v0 = *(const bf16x8*)(vrow + ((hi * 16) ^ rsw));
                bf16x8 v1 = *(const bf16x8*)(vrow + ((32 + hi * 16) ^ rsw));
                bf16x8 v2 = *(const bf16x8*)(vrow + ((64 + hi * 16) ^ rsw));
                bf16x8 v3 = *(const bf16x8*)(vrow + ((96 + hi * 16) ^ rsw));
                acc[db] = __builtin_amdgcn_mfma_f32_32x32x16_bf16(v0, pf[0], acc[db], 0, 0, 0);
                acc[db] = __builtin_amdgcn_mfma_f32_32x32x16_bf16(v1, pf[1], acc[db], 0, 0, 0);
                acc[db] = __builtin_amdgcn_mfma_f32_32x32x16_bf16(v2, pf[2], acc[db], 0, 0, 0);
                acc[db] = __builtin_amdgcn_mfma_f32_32x32x16_bf16(v3, pf[3], acc[db], 0, 0, 0);
            }
        }
        __syncthreads();
    }

    float rl = __builtin_amdgcn_rcpf(l);
    short* orow = Ob + ((size_t)(bb * S_ + q)) * E_ + hh * 64;
#pragma unroll
    for (int db = 0; db < 2; ++db)
#pragma unroll
        for (int rb = 0; rb < 4; ++rb) {
            uint2v pk;
            pk[0] = cvtpk(acc[db][rb * 4 + 0] * rl, acc[db][rb * 4 + 1] * rl);
            pk[1] = cvtpk(acc[db][rb * 4 + 2] * rl, acc[db][rb * 4 + 3] * rl);
            *(uint2v*)&orow[db * 32 + rb * 8 + hi * 4] = pk;
        }
}

extern "C" void kernel_launch(void* const* d_in, const int* in_sizes, int n_in,
                              void* d_out, int out_size, void* d_ws, size_t ws_size,
                              hipStream_t stream) {
    const float* x      = (const float*)d_in[0];
    const float* w_attn = (const float*)d_in[1];
    const float* b_attn = (const float*)d_in[2];
    const float* w_out  = (const float*)d_in[3];
    const float* b_out  = (const float*)d_in[4];
    float* out = (float*)d_out;

    char* ws = (char*)d_ws;
    short* Xbf  = (short*)(ws);                       // 16 MB (reused as attn output)
    short* Wat  = (short*)(ws + (16ull << 20));       // 6 MB  [3072][1024]
    short* Wot  = (short*)(ws + (22ull << 20));       // 2 MB  [1024][1024]
    short* Qb   = (short*)(ws + (24ull << 20));       // 16 MB flat [8192][1024]
    short* Kb   = (short*)(ws + (40ull << 20));       // 16 MB flat [8192][1024]
    short* Vt   = (short*)(ws + (56ull << 20));       // 16 MB [B,H,D,S]
    short* Obuf = Xbf;

    convert_f32_bf16<<<2048, 256, 0, stream>>>(x, Xbf, M_ * E_);
    transpose_convert<<<dim3(N1_ / 32, E_ / 32), dim3(32, 8), 0, stream>>>(w_attn, Wat, E_, N1_);
    transpose_convert<<<dim3(E_ / 32, E_ / 32), dim3(32, 8), 0, stream>>>(w_out, Wot, E_, E_);

    gemm_qkv<<<1024, 256, 0, stream>>>(Xbf, Wat, b_attn, Qb, Kb, Vt);

    attn_kernel<<<1024, 256, 0, stream>>>(Qb, Kb, Vt, Obuf);

    gemm_out8<<<256, 512, 0, stream>>>(Obuf, Wot, b_out, out);
}

// Round 16
// 155.460 us; speedup vs baseline: 1.2369x; 1.0462x over previous
//
#include <hip/hip_runtime.h>

typedef short bf16x8 __attribute__((ext_vector_type(8)));
typedef float f32x4 __attribute__((ext_vector_type(4)));
typedef float f32x16 __attribute__((ext_vector_type(16)));
typedef float float4v __attribute__((ext_vector_type(4)));
typedef short short4v __attribute__((ext_vector_type(4)));
typedef unsigned uint2v __attribute__((ext_vector_type(2)));
typedef unsigned uint4v __attribute__((ext_vector_type(4)));

#define B_ 4
#define S_ 2048
#define E_ 1024
#define H_ 16
#define D_ 64
#define M_ (B_*S_)      // 8192
#define N1_ (3*E_)      // 3072

__device__ inline short f2bs(float f) {
    unsigned u = __builtin_bit_cast(unsigned, f);
    unsigned r = u + 0x7fffu + ((u >> 16) & 1u);
    return (short)(r >> 16);
}
__device__ inline float exp2a(float x) {
    float r; asm("v_exp_f32 %0, %1" : "=v"(r) : "v"(x)); return r;
}
__device__ inline unsigned cvtpk(float a, float b) {
    unsigned r; asm("v_cvt_pk_bf16_f32 %0, %1, %2" : "=v"(r) : "v"(a), "v"(b)); return r;
}

__device__ inline const __attribute__((address_space(1))) void* gas(const void* p) {
    return (const __attribute__((address_space(1))) void*)p;
}
__device__ inline __attribute__((address_space(3))) void* las(void* p) {
    return (__attribute__((address_space(3))) void*)p;
}

// ---------------- fused prologue: convert x + transpose both weights ----------------
// blocks [0,2048): x fp32->bf16 (grid-stride over 8M elems)
// blocks [2048,5120): w_attn [1024][3072] -> Wat [3072][1024] bf16  (96x32 tiles)
// blocks [5120,6144): w_out  [1024][1024] -> Wot [1024][1024] bf16  (32x32 tiles)
__global__ __launch_bounds__(256) void prologue(
    const float* __restrict__ x, short* __restrict__ Xbf,
    const float* __restrict__ w_attn, short* __restrict__ Wat,
    const float* __restrict__ w_out, short* __restrict__ Wot) {
    __shared__ float t[32][33];
    const int bid = blockIdx.x;
    const int tid = threadIdx.x;
    if (bid < 2048) {
        const int n = M_ * E_;
        const int stride = 2048 * 256 * 4;
        for (int i = (bid * 256 + tid) * 4; i < n; i += stride) {
            float4v v = *(const float4v*)&x[i];
            short4v o;
            o[0] = f2bs(v[0]); o[1] = f2bs(v[1]); o[2] = f2bs(v[2]); o[3] = f2bs(v[3]);
            *(short4v*)&Xbf[i] = o;
        }
    } else {
        const float* in;
        short* out;
        int rows, cols, bx, by;
        if (bid < 5120) {
            in = w_attn; out = Wat; rows = E_; cols = N1_;
            int b2 = bid - 2048;             // grid was (96, 32)
            bx = (b2 % 96) * 32; by = (b2 / 96) * 32;
        } else {
            in = w_out; out = Wot; rows = E_; cols = E_;
            int b2 = bid - 5120;             // grid was (32, 32)
            bx = (b2 & 31) * 32; by = (b2 >> 5) * 32;
        }
        const int tx = tid & 31, ty = tid >> 5;  // (32, 8)
#pragma unroll
        for (int i = 0; i < 4; ++i)
            t[ty + i * 8][tx] = in[(size_t)(by + ty + i * 8) * cols + bx + tx];
        __syncthreads();
#pragma unroll
        for (int i = 0; i < 4; ++i)
            out[(size_t)(bx + ty + i * 8) * rows + by + tx] = f2bs(t[tx][ty + i * 8]);
    }
}

#define VMW(n) asm volatile("s_waitcnt vmcnt(" #n ")" ::: "memory")
#define NOP_ ((void)0)

// ================= 128x192 GEMM (QKV), 256 thr, 80KB LDS -> 2 blocks/CU =================
#define QKV_MFMA(Q) \
    _Pragma("unroll") for (int nf = 0; nf < 6; ++nf) { \
        acc[(Q)][nf] = __builtin_amdgcn_mfma_f32_16x16x32_bf16(af[0], bfrag[nf][0], acc[(Q)][nf], 0, 0, 0); \
        acc[(Q)][nf] = __builtin_amdgcn_mfma_f32_16x16x32_bf16(af[1], bfrag[nf][1], acc[(Q)][nf], 0, 0, 0); \
    }

#define QKV_PHASE(Q, STAGE_STMT, WAITV) do { \
    bf16x8 af[2]; \
    const char* lAq = lA + (Q) * 4096; \
    _Pragma("unroll") for (int ks = 0; ks < 2; ++ks) \
        af[ks] = *(const bf16x8*)(lAq + li * 128 + ((ks * 64 + g * 16) ^ ((li & 7) << 4))); \
    STAGE_STMT; \
    __builtin_amdgcn_s_barrier(); \
    asm volatile("s_waitcnt lgkmcnt(0)" ::: "memory"); \
    __builtin_amdgcn_sched_barrier(0); \
    __builtin_amdgcn_s_setprio(1); \
    QKV_MFMA(Q); \
    __builtin_amdgcn_s_setprio(0); \
    WAITV; \
    __builtin_amdgcn_s_barrier(); \
} while (0)

__global__ __launch_bounds__(256, 2) void gemm_qkv(
    const short* __restrict__ A, const short* __restrict__ Bt,
    const float* __restrict__ bias,
    short* __restrict__ Qb, short* __restrict__ Kb, short* __restrict__ Vt) {
    __shared__ __attribute__((aligned(16))) short ldsA[2][8192];   // [buf][4 calls][2 wr][16r][64k]
    __shared__ __attribute__((aligned(16))) short ldsB[2][12288];  // [buf][192r][64k]
    const int tid = threadIdx.x;
    const int lane = tid & 63;
    const int wid = tid >> 6;
    const int li = lane & 15, g = lane >> 4;
    const int wr = wid >> 1, wc = wid & 1;
    const int Kdim = E_;
    const int NT = Kdim >> 6;  // 16

    const int id = blockIdx.x;
    const int swz = (id & 7) * 128 + (id >> 3);
    const int bx = swz & 15, by = swz >> 4;
    const int row0 = by * 128, col0 = bx * 192;

    const int lr8 = lane >> 3;
    const int cstage = (((lane & 7) ^ (lr8 & 7)) << 4);

    auto stageA = [&](int buf, int kt) {
#pragma unroll
        for (int Q = 0; Q < 4; ++Q) {
            int grow = (wid >> 1) * 64 + Q * 16 + (wid & 1) * 8 + lr8;
            const char* src = (const char*)A +
                ((size_t)(row0 + grow) * Kdim + kt * 64) * 2 + cstage;
            char* dst = (char*)&ldsA[buf][0] + Q * 4096 + wid * 1024;
            __builtin_amdgcn_global_load_lds(gas(src), las(dst), 16, 0, 0);
        }
    };
    auto stageB = [&](int buf, int kt) {
#pragma unroll
        for (int i = 0; i < 6; ++i) {
            int grow = i * 32 + wid * 8 + lr8;
            const char* src = (const char*)Bt +
                ((size_t)(col0 + grow) * Kdim + kt * 64) * 2 + cstage;
            char* dst = (char*)&ldsB[buf][0] + i * 4096 + wid * 1024;
            __builtin_amdgcn_global_load_lds(gas(src), las(dst), 16, 0, 0);
        }
    };

    f32x4 acc[4][6];
#pragma unroll
    for (int m = 0; m < 4; ++m)
#pragma unroll
        for (int n = 0; n < 6; ++n) acc[m][n] = (f32x4){0.f, 0.f, 0.f, 0.f};

    stageB(0, 0);
    stageA(0, 0);
    asm volatile("s_waitcnt vmcnt(0)" ::: "memory");
    __syncthreads();

    for (int t = 0; t < NT; ++t) {
        const int cur = t & 1;
        const int nb = cur ^ 1;
        const int tn = t + 1;
        const bool st = (tn < NT);
        const char* lA = (const char*)&ldsA[cur][0] + wr * 2048;
        const char* lB = (const char*)&ldsB[cur][0];

        bf16x8 bfrag[6][2];
#pragma unroll
        for (int nf = 0; nf < 6; ++nf)
#pragma unroll
            for (int ks = 0; ks < 2; ++ks) {
                int r = wc * 96 + nf * 16 + li;
                bfrag[nf][ks] = *(const bf16x8*)(lB + r * 128 + ((ks * 64 + g * 16) ^ ((r & 7) << 4)));
            }
        if (st) {
            QKV_PHASE(0, stageB(nb, tn), NOP_);
            QKV_PHASE(1, stageA(nb, tn), VMW(8));
            QKV_PHASE(2, NOP_, NOP_);
            QKV_PHASE(3, NOP_, VMW(2));
        } else {
            QKV_PHASE(0, NOP_, NOP_);
            QKV_PHASE(1, NOP_, VMW(0));
            QKV_PHASE(2, NOP_, NOP_);
            QKV_PHASE(3, NOP_, NOP_);
        }
    }

    // ---- epilogue ----
#pragma unroll
    for (int nf = 0; nf < 6; ++nf) {
        int ncolg = col0 + wc * 96 + nf * 16 + li;
        float bv = bias[ncolg];
        int part = ncolg >> 10;
        int rem = ncolg & 1023;
        if (part < 2) {
            short* Dst = (part == 0) ? Qb : Kb;
#pragma unroll
            for (int mi = 0; mi < 4; ++mi) {
                int rbase = row0 + wr * 64 + mi * 16 + 4 * g;
#pragma unroll
                for (int j = 0; j < 4; ++j)
                    Dst[(size_t)(rbase + j) * E_ + rem] = f2bs(acc[mi][nf][j] + bv);
            }
        } else {
            int h = rem >> 6, d = rem & 63;
#pragma unroll
            for (int mi = 0; mi < 4; ++mi) {
                int s0 = row0 + wr * 64 + mi * 16 + 4 * g;
                int bb2 = s0 >> 11;
                int ss = s0 & 2047;
                uint2v p;
                p[0] = cvtpk(acc[mi][nf][0] + bv, acc[mi][nf][1] + bv);
                p[1] = cvtpk(acc[mi][nf][2] + bv, acc[mi][nf][3] + bv);
                *(uint2v*)&Vt[((size_t)(bb2 * H_ + h) * D_ + d) * S_ + ss] = p;
            }
        }
    }
}

// ================= 128x128 GEMM (out-proj), 256 thr, 64KB LDS -> 2 blocks/CU =================
// Grid 64x8 = 512 = 2x256 exact. Same structure as gemm_qkv with nf=4, fp32 epilogue.
#define OUT_MFMA(Q) \
    _Pragma("unroll") for (int nf = 0; nf < 4; ++nf) { \
        acc[(Q)][nf] = __builtin_amdgcn_mfma_f32_16x16x32_bf16(af[0], bfrag[nf][0], acc[(Q)][nf], 0, 0, 0); \
        acc[(Q)][nf] = __builtin_amdgcn_mfma_f32_16x16x32_bf16(af[1], bfrag[nf][1], acc[(Q)][nf], 0, 0, 0); \
    }

#define OUT_PHASE(Q, STAGE_STMT, WAITV) do { \
    bf16x8 af[2]; \
    const char* lAq = lA + (Q) * 4096; \
    _Pragma("unroll") for (int ks = 0; ks < 2; ++ks) \
        af[ks] = *(const bf16x8*)(lAq + li * 128 + ((ks * 64 + g * 16) ^ ((li & 7) << 4))); \
    STAGE_STMT; \
    __builtin_amdgcn_s_barrier(); \
    asm volatile("s_waitcnt lgkmcnt(0)" ::: "memory"); \
    __builtin_amdgcn_sched_barrier(0); \
    __builtin_amdgcn_s_setprio(1); \
    OUT_MFMA(Q); \
    __builtin_amdgcn_s_setprio(0); \
    WAITV; \
    __builtin_amdgcn_s_barrier(); \
} while (0)

__global__ __launch_bounds__(256, 2) void gemm_out(
    const short* __restrict__ A, const short* __restrict__ Bt,
    const float* __restrict__ bias, float* __restrict__ Cf) {
    __shared__ __attribute__((aligned(16))) short ldsA[2][8192];  // [buf][4 calls][2 wr][16r][64k]
    __shared__ __attribute__((aligned(16))) short ldsB[2][8192];  // [buf][128r][64k]
    const int tid = threadIdx.x;
    const int lane = tid & 63;
    const int wid = tid >> 6;
    const int li = lane & 15, g = lane >> 4;
    const int wr = wid >> 1, wc = wid & 1;
    const int Kdim = E_;
    const int NT = Kdim >> 6;  // 16

    // bijective XCD swizzle: nwg=512, 512/8=64
    const int id = blockIdx.x;
    const int swz = (id & 7) * 64 + (id >> 3);
    const int bx = swz & 7, by = swz >> 3;       // 8 col-tiles, 64 row-tiles
    const int row0 = by * 128, col0 = bx * 128;

    const int lr8 = lane >> 3;
    const int cstage = (((lane & 7) ^ (lr8 & 7)) << 4);

    auto stageA = [&](int buf, int kt) {
#pragma unroll
        for (int Q = 0; Q < 4; ++Q) {
            int grow = (wid >> 1) * 64 + Q * 16 + (wid & 1) * 8 + lr8;
            const char* src = (const char*)A +
                ((size_t)(row0 + grow) * Kdim + kt * 64) * 2 + cstage;
            char* dst = (char*)&ldsA[buf][0] + Q * 4096 + wid * 1024;
            __builtin_amdgcn_global_load_lds(gas(src), las(dst), 16, 0, 0);
        }
    };
    auto stageB = [&](int buf, int kt) {
#pragma unroll
        for (int i = 0; i < 4; ++i) {
            int grow = i * 32 + wid * 8 + lr8;
            const char* src = (const char*)Bt +
                ((size_t)(col0 + grow) * Kdim + kt * 64) * 2 + cstage;
            char* dst = (char*)&ldsB[buf][0] + i * 4096 + wid * 1024;
            __builtin_amdgcn_global_load_lds(gas(src), las(dst), 16, 0, 0);
        }
    };

    f32x4 acc[4][4];
#pragma unroll
    for (int m = 0; m < 4; ++m)
#pragma unroll
        for (int n = 0; n < 4; ++n) acc[m][n] = (f32x4){0.f, 0.f, 0.f, 0.f};

    stageB(0, 0);
    stageA(0, 0);
    asm volatile("s_waitcnt vmcnt(0)" ::: "memory");
    __syncthreads();

    for (int t = 0; t < NT; ++t) {
        const int cur = t & 1;
        const int nb = cur ^ 1;
        const int tn = t + 1;
        const bool st = (tn < NT);
        const char* lA = (const char*)&ldsA[cur][0] + wr * 2048;
        const char* lB = (const char*)&ldsB[cur][0];

        bf16x8 bfrag[4][2];
#pragma unroll
        for (int nf = 0; nf < 4; ++nf)
#pragma unroll
            for (int ks = 0; ks < 2; ++ks) {
                int r = wc * 64 + nf * 16 + li;
                bfrag[nf][ks] = *(const bf16x8*)(lB + r * 128 + ((ks * 64 + g * 16) ^ ((r & 7) << 4)));
            }
        if (st) {
            OUT_PHASE(0, stageB(nb, tn), NOP_);
            OUT_PHASE(1, stageA(nb, tn), VMW(8));
            OUT_PHASE(2, NOP_, NOP_);
            OUT_PHASE(3, NOP_, VMW(2));
        } else {
            OUT_PHASE(0, NOP_, NOP_);
            OUT_PHASE(1, NOP_, VMW(0));
            OUT_PHASE(2, NOP_, NOP_);
            OUT_PHASE(3, NOP_, NOP_);
        }
    }

    // ---- epilogue: fp32 + bias ----
#pragma unroll
    for (int nf = 0; nf < 4; ++nf) {
        int ncol = col0 + wc * 64 + nf * 16 + li;
        float bv = bias[ncol];
#pragma unroll
        for (int mi = 0; mi < 4; ++mi) {
            int rbase = row0 + wr * 64 + mi * 16 + 4 * g;
#pragma unroll
            for (int j = 0; j < 4; ++j)
                Cf[(size_t)(rbase + j) * E_ + ncol] = acc[mi][nf][j] + bv;
        }
    }
}

// ---------------- causal flash attention v9 (R15 verified) ----------------
#define GRP 1040
__global__ __launch_bounds__(256, 4) void attn_kernel(
    const short* __restrict__ Qb, const short* __restrict__ Kb,
    const short* __restrict__ Vt, short* __restrict__ Ob) {
    __shared__ __attribute__((aligned(16))) char Kl[8 * GRP];
    __shared__ __attribute__((aligned(16))) char Vl[8 * GRP];
    const int lane = threadIdx.x & 63;
    const int wv = threadIdx.x >> 6;
    const int l31 = lane & 31;
    const int hi = lane >> 5;
    const int id = blockIdx.x;
    const int xcd = id & 7;
    const int r_ = id >> 3;
    const int qt = 15 - (r_ >> 3);
    const int bh = xcd * 8 + (r_ & 7);
    const int bb = bh >> 4, hh = bh & 15;
    const short* Qh = Qb + (size_t)bb * (S_ * E_) + hh * 64;
    const short* Kh = Kb + (size_t)bb * (S_ * E_) + hh * 64;
    const short* Vh = Vt + (size_t)bh * (D_ * S_);
    const float CEXP = 0.18033688011112042f;

    const int rstage = wv * 8 + (lane >> 3);
    const int cstage = (((lane & 7) ^ ((lane >> 3) & 7)) << 4);

    const int q0w = qt * 128 + wv * 32;
    const int q = q0w + l31;

    bf16x8 qf[4];
#pragma unroll
    for (int c = 0; c < 4; ++c)
        qf[c] = *(const bf16x8*)&Qh[(size_t)q * E_ + c * 16 + hi * 8];

    f32x16 acc[2];
#pragma unroll
    for (int d = 0; d < 2; ++d)
#pragma unroll
        for (int r = 0; r < 16; ++r) acc[d][r] = 0.f;
    float m = -3e38f, mC = 0.f, l = 0.f;

    const int nw = (q0w + 95) >> 6;
    const int nt = (qt * 128 + 191) >> 6;

    const int kg0 = (l31 >> 3) * GRP + (l31 & 7) * 128;
    const int kg1 = ((32 + l31) >> 3) * GRP + (l31 & 7) * 128;
    const int ksw = (l31 & 7) << 4;

    for (int it = 0; it < nt; ++it) {
        const int kt0 = it * 64;
#pragma unroll
        for (int half = 0; half < 2; ++half) {
            const int grp = half * 4 + wv;
            const char* gk = (const char*)(Kh + (size_t)(kt0 + half * 32 + rstage) * E_) + cstage;
            __builtin_amdgcn_global_load_lds(gas(gk), las(Kl + grp * GRP), 16, 0, 0);
            const char* gv = (const char*)Vh + (size_t)(half * 32 + rstage) * (S_ * 2) + (size_t)kt0 * 2 + cstage;
            __builtin_amdgcn_global_load_lds(gas(gv), las(Vl + grp * GRP), 16, 0, 0);
        }
        __syncthreads();
        if (it < nw) {
            f32x16 sc0, sc1;
#pragma unroll
            for (int r = 0; r < 16; ++r) { sc0[r] = 0.f; sc1[r] = 0.f; }
#pragma unroll
            for (int c = 0; c < 4; ++c) {
                bf16x8 kf0 = *(const bf16x8*)(Kl + kg0 + ((c * 32 + hi * 16) ^ ksw));
                bf16x8 kf1 = *(const bf16x8*)(Kl + kg1 + ((c * 32 + hi * 16) ^ ksw));
                sc0 = __builtin_amdgcn_mfma_f32_32x32x16_bf16(kf0, qf[c], sc0, 0, 0, 0);
                sc1 = __builtin_amdgcn_mfma_f32_32x32x16_bf16(kf1, qf[c], sc1, 0, 0, 0);
            }
            if (kt0 + 63 > q0w) {
                const int kb = kt0 + 4 * hi;
#pragma unroll
                for (int r = 0; r < 16; ++r) {
                    int key = kb + (r & 3) + 8 * (r >> 2);
                    sc0[r] = (key > q) ? -3e38f : sc0[r];
                    sc1[r] = (key + 32 > q) ? -3e38f : sc1[r];
                }
            }
            float tmx[8];
#pragma unroll
            for (int r = 0; r < 8; ++r)
                tmx[r] = fmaxf(fmaxf(sc0[2 * r], sc0[2 * r + 1]),
                               fmaxf(sc1[2 * r], sc1[2 * r + 1]));
            float tm = fmaxf(fmaxf(fmaxf(tmx[0], tmx[1]), fmaxf(tmx[2], tmx[3])),
                             fmaxf(fmaxf(tmx[4], tmx[5]), fmaxf(tmx[6], tmx[7])));
            tm = fmaxf(tm, __shfl_xor(tm, 32, 64));
            bool need = (tm > m + 16.0f);
            if (__ballot((int)need) != 0ull) {
                float mn = fmaxf(m, tm);
                float sf = exp2a((m - mn) * CEXP);
                m = mn; mC = mn * CEXP;
                l *= sf;
#pragma unroll
                for (int d = 0; d < 2; ++d)
#pragma unroll
                    for (int r = 0; r < 16; ++r) acc[d][r] *= sf;
            }
#pragma unroll
            for (int r = 0; r < 16; ++r) {
                sc0[r] = exp2a(fmaf(sc0[r], CEXP, -mC));
                sc1[r] = exp2a(fmaf(sc1[r], CEXP, -mC));
            }
            float s0 = 0.f, s1 = 0.f;
#pragma unroll
            for (int r = 0; r < 8; ++r) {
                s0 += sc0[2 * r] + sc0[2 * r + 1];
                s1 += sc1[2 * r] + sc1[2 * r + 1];
            }
            float ls = s0 + s1;
            ls += __shfl_xor(ls, 32, 64);
            l += ls;
            bf16x8 pf[4];
#pragma unroll
            for (int s = 0; s < 2; ++s) {
                const f32x16& p = s ? sc1 : sc0;
                unsigned a0 = cvtpk(p[0], p[1]),   a1 = cvtpk(p[2], p[3]);
                unsigned b0 = cvtpk(p[4], p[5]),   b1 = cvtpk(p[6], p[7]);
                unsigned a2 = cvtpk(p[8], p[9]),   a3 = cvtpk(p[10], p[11]);
                unsigned b2 = cvtpk(p[12], p[13]), b3 = cvtpk(p[14], p[15]);
                asm volatile("v_permlane32_swap_b32 %0, %1" : "+v"(a0), "+v"(b0));
                asm volatile("v_permlane32_swap_b32 %0, %1" : "+v"(a1), "+v"(b1));
                asm volatile("v_permlane32_swap_b32 %0, %1" : "+v"(a2), "+v"(b2));
                asm volatile("v_permlane32_swap_b32 %0, %1" : "+v"(a3), "+v"(b3));
                uint4v u1, u2;
                u1[0] = a0; u1[1] = a1; u1[2] = b0; u1[3] = b1;
                u2[0] = a2; u2[1] = a3; u2[2] = b2; u2[3] = b3;
                pf[s * 2] = __builtin_bit_cast(bf16x8, u1);
                pf[s * 2 + 1] = __builtin_bit_cast(bf16x8, u2);
            }
#pragma unroll
            for (int db = 0; db < 2; ++db) {
                const int row = db * 32 + l31;
                const int rsw = (row & 7) << 4;
                const char* vrow = Vl + (row >> 3) * GRP + (row & 7) * 128;
                bf16x8 v0 = *(const bf16x8*)(vrow + ((hi * 16) ^ rsw));
                bf16x8 v1 = *(const bf16x8*)(vrow + ((32 + hi * 16) ^ rsw));
                bf16x8 v2 = *(const bf16x8*)(vrow + ((64 + hi * 16) ^ rsw));
                bf16x8 v3 = *(const bf16x8*)(vrow + ((96 + hi * 16) ^ rsw));
                acc[db] = __builtin_amdgcn_mfma_f32_32x32x16_bf16(v0, pf[0], acc[db], 0, 0, 0);
                acc[db] = __builtin_amdgcn_mfma_f32_32x32x16_bf16(v1, pf[1], acc[db], 0, 0, 0);
                acc[db] = __builtin_amdgcn_mfma_f32_32x32x16_bf16(v2, pf[2], acc[db], 0, 0, 0);
                acc[db] = __builtin_amdgcn_mfma_f32_32x32x16_bf16(v3, pf[3], acc[db], 0, 0, 0);
            }
        }
        __syncthreads();
    }

    float rl = __builtin_amdgcn_rcpf(l);
    short* orow = Ob + ((size_t)(bb * S_ + q)) * E_ + hh * 64;
#pragma unroll
    for (int db = 0; db < 2; ++db)
#pragma unroll
        for (int rb = 0; rb < 4; ++rb) {
            uint2v pk;
            pk[0] = cvtpk(acc[db][rb * 4 + 0] * rl, acc[db][rb * 4 + 1] * rl);
            pk[1] = cvtpk(acc[db][rb * 4 + 2] * rl, acc[db][rb * 4 + 3] * rl);
            *(uint2v*)&orow[db * 32 + rb * 8 + hi * 4] = pk;
        }
}

extern "C" void kernel_launch(void* const* d_in, const int* in_sizes, int n_in,
                              void* d_out, int out_size, void* d_ws, size_t ws_size,
                              hipStream_t stream) {
    const float* x      = (const float*)d_in[0];
    const float* w_attn = (const float*)d_in[1];
    const float* b_attn = (const float*)d_in[2];
    const float* w_out  = (const float*)d_in[3];
    const float* b_out  = (const float*)d_in[4];
    float* out = (float*)d_out;

    char* ws = (char*)d_ws;
    short* Xbf  = (short*)(ws);                       // 16 MB (reused as attn output)
    short* Wat  = (short*)(ws + (16ull << 20));       // 6 MB  [3072][1024]
    short* Wot  = (short*)(ws + (22ull << 20));       // 2 MB  [1024][1024]
    short* Qb   = (short*)(ws + (24ull << 20));       // 16 MB flat [8192][1024]
    short* Kb   = (short*)(ws + (40ull << 20));       // 16 MB flat [8192][1024]
    short* Vt   = (short*)(ws + (56ull << 20));       // 16 MB [B,H,D,S]
    short* Obuf = Xbf;

    prologue<<<6144, 256, 0, stream>>>(x, Xbf, w_attn, Wat, w_out, Wot);

    gemm_qkv<<<1024, 256, 0, stream>>>(Xbf, Wat, b_attn, Qb, Kb, Vt);

    attn_kernel<<<1024, 256, 0, stream>>>(Qb, Kb, Vt, Obuf);

    gemm_out<<<512, 256, 0, stream>>>(Obuf, Wot, b_out, out);
}

// Round 17
// 151.409 us; speedup vs baseline: 1.2700x; 1.0268x over previous
//
#include <hip/hip_runtime.h>

typedef short bf16x8 __attribute__((ext_vector_type(8)));
typedef float f32x4 __attribute__((ext_vector_type(4)));
typedef float f32x16 __attribute__((ext_vector_type(16)));
typedef float float4v __attribute__((ext_vector_type(4)));
typedef short short4v __attribute__((ext_vector_type(4)));
typedef unsigned uint2v __attribute__((ext_vector_type(2)));
typedef unsigned uint4v __attribute__((ext_vector_type(4)));

#define B_ 4
#define S_ 2048
#define E_ 1024
#define H_ 16
#define D_ 64
#define M_ (B_*S_)      // 8192
#define N1_ (3*E_)      // 3072

__device__ inline short f2bs(float f) {
    unsigned u = __builtin_bit_cast(unsigned, f);
    unsigned r = u + 0x7fffu + ((u >> 16) & 1u);
    return (short)(r >> 16);
}
__device__ inline float exp2a(float x) {
    float r; asm("v_exp_f32 %0, %1" : "=v"(r) : "v"(x)); return r;
}
__device__ inline unsigned cvtpk(float a, float b) {
    unsigned r; asm("v_cvt_pk_bf16_f32 %0, %1, %2" : "=v"(r) : "v"(a), "v"(b)); return r;
}

__device__ inline const __attribute__((address_space(1))) void* gas(const void* p) {
    return (const __attribute__((address_space(1))) void*)p;
}
__device__ inline __attribute__((address_space(3))) void* las(void* p) {
    return (__attribute__((address_space(3))) void*)p;
}

// ---------------- fused prologue (R16 verified) ----------------
__global__ __launch_bounds__(256) void prologue(
    const float* __restrict__ x, short* __restrict__ Xbf,
    const float* __restrict__ w_attn, short* __restrict__ Wat,
    const float* __restrict__ w_out, short* __restrict__ Wot) {
    __shared__ float t[32][33];
    const int bid = blockIdx.x;
    const int tid = threadIdx.x;
    if (bid < 2048) {
        const int n = M_ * E_;
        const int stride = 2048 * 256 * 4;
        for (int i = (bid * 256 + tid) * 4; i < n; i += stride) {
            float4v v = *(const float4v*)&x[i];
            short4v o;
            o[0] = f2bs(v[0]); o[1] = f2bs(v[1]); o[2] = f2bs(v[2]); o[3] = f2bs(v[3]);
            *(short4v*)&Xbf[i] = o;
        }
    } else {
        const float* in;
        short* out;
        int rows, cols, bx, by;
        if (bid < 5120) {
            in = w_attn; out = Wat; rows = E_; cols = N1_;
            int b2 = bid - 2048;
            bx = (b2 % 96) * 32; by = (b2 / 96) * 32;
        } else {
            in = w_out; out = Wot; rows = E_; cols = E_;
            int b2 = bid - 5120;
            bx = (b2 & 31) * 32; by = (b2 >> 5) * 32;
        }
        const int tx = tid & 31, ty = tid >> 5;
#pragma unroll
        for (int i = 0; i < 4; ++i)
            t[ty + i * 8][tx] = in[(size_t)(by + ty + i * 8) * cols + bx + tx];
        __syncthreads();
#pragma unroll
        for (int i = 0; i < 4; ++i)
            out[(size_t)(bx + ty + i * 8) * rows + by + tx] = f2bs(t[tx][ty + i * 8]);
    }
}

#define VMW(n) asm volatile("s_waitcnt vmcnt(" #n ")" ::: "memory")
#define NOP_ ((void)0)

// ================= 128x192 GEMM (QKV), 2 merged phases/tile, 2 blocks/CU =================
// PH_A: reads B-frags + A-Q0/Q1, stages B(t+1), 24 MFMA, VMW(6).
// PH_B: reads A-Q2/Q3, stages A(t+1), 24 MFMA, VMW(2).
// Invariant: A-Q2,Q3(t+1) in flight across the tile boundary.
#define QKV_MFMA1(Q, AF) \
    _Pragma("unroll") for (int nf = 0; nf < 6; ++nf) { \
        acc[(Q)][nf] = __builtin_amdgcn_mfma_f32_16x16x32_bf16(AF[0], bfrag[nf][0], acc[(Q)][nf], 0, 0, 0); \
        acc[(Q)][nf] = __builtin_amdgcn_mfma_f32_16x16x32_bf16(AF[1], bfrag[nf][1], acc[(Q)][nf], 0, 0, 0); \
    }

#define QKV_PHASE2(QA, STAGE_STMT, WAITV) do { \
    bf16x8 afA[2], afB[2]; \
    const char* lA0 = lA + (QA) * 4096; \
    const char* lA1 = lA + ((QA) + 1) * 4096; \
    _Pragma("unroll") for (int ks = 0; ks < 2; ++ks) { \
        afA[ks] = *(const bf16x8*)(lA0 + li * 128 + ((ks * 64 + g * 16) ^ ((li & 7) << 4))); \
        afB[ks] = *(const bf16x8*)(lA1 + li * 128 + ((ks * 64 + g * 16) ^ ((li & 7) << 4))); \
    } \
    STAGE_STMT; \
    __builtin_amdgcn_s_barrier(); \
    asm volatile("s_waitcnt lgkmcnt(0)" ::: "memory"); \
    __builtin_amdgcn_sched_barrier(0); \
    __builtin_amdgcn_s_setprio(1); \
    QKV_MFMA1(QA, afA); \
    QKV_MFMA1((QA) + 1, afB); \
    __builtin_amdgcn_s_setprio(0); \
    WAITV; \
    __builtin_amdgcn_s_barrier(); \
} while (0)

__global__ __launch_bounds__(256, 2) void gemm_qkv(
    const short* __restrict__ A, const short* __restrict__ Bt,
    const float* __restrict__ bias,
    short* __restrict__ Qb, short* __restrict__ Kb, short* __restrict__ Vt) {
    __shared__ __attribute__((aligned(16))) short ldsA[2][8192];   // [buf][4 calls][2 wr][16r][64k]
    __shared__ __attribute__((aligned(16))) short ldsB[2][12288];  // [buf][192r][64k]
    const int tid = threadIdx.x;
    const int lane = tid & 63;
    const int wid = tid >> 6;
    const int li = lane & 15, g = lane >> 4;
    const int wr = wid >> 1, wc = wid & 1;
    const int Kdim = E_;
    const int NT = Kdim >> 6;  // 16

    const int id = blockIdx.x;
    const int swz = (id & 7) * 128 + (id >> 3);
    const int bx = swz & 15, by = swz >> 4;
    const int row0 = by * 128, col0 = bx * 192;

    const int lr8 = lane >> 3;
    const int cstage = (((lane & 7) ^ (lr8 & 7)) << 4);

    auto stageA = [&](int buf, int kt) {
#pragma unroll
        for (int Q = 0; Q < 4; ++Q) {
            int grow = (wid >> 1) * 64 + Q * 16 + (wid & 1) * 8 + lr8;
            const char* src = (const char*)A +
                ((size_t)(row0 + grow) * Kdim + kt * 64) * 2 + cstage;
            char* dst = (char*)&ldsA[buf][0] + Q * 4096 + wid * 1024;
            __builtin_amdgcn_global_load_lds(gas(src), las(dst), 16, 0, 0);
        }
    };
    auto stageB = [&](int buf, int kt) {
#pragma unroll
        for (int i = 0; i < 6; ++i) {
            int grow = i * 32 + wid * 8 + lr8;
            const char* src = (const char*)Bt +
                ((size_t)(col0 + grow) * Kdim + kt * 64) * 2 + cstage;
            char* dst = (char*)&ldsB[buf][0] + i * 4096 + wid * 1024;
            __builtin_amdgcn_global_load_lds(gas(src), las(dst), 16, 0, 0);
        }
    };

    f32x4 acc[4][6];
#pragma unroll
    for (int m = 0; m < 4; ++m)
#pragma unroll
        for (int n = 0; n < 6; ++n) acc[m][n] = (f32x4){0.f, 0.f, 0.f, 0.f};

    stageB(0, 0);
    stageA(0, 0);
    asm volatile("s_waitcnt vmcnt(0)" ::: "memory");
    __syncthreads();

    for (int t = 0; t < NT; ++t) {
        const int cur = t & 1;
        const int nb = cur ^ 1;
        const int tn = t + 1;
        const bool st = (tn < NT);
        const char* lA = (const char*)&ldsA[cur][0] + wr * 2048;
        const char* lB = (const char*)&ldsB[cur][0];

        bf16x8 bfrag[6][2];
#pragma unroll
        for (int nf = 0; nf < 6; ++nf)
#pragma unroll
            for (int ks = 0; ks < 2; ++ks) {
                int r = wc * 96 + nf * 16 + li;
                bfrag[nf][ks] = *(const bf16x8*)(lB + r * 128 + ((ks * 64 + g * 16) ^ ((r & 7) << 4)));
            }
        if (st) {
            QKV_PHASE2(0, stageB(nb, tn), VMW(6));
            QKV_PHASE2(2, stageA(nb, tn), VMW(2));
        } else {
            QKV_PHASE2(0, NOP_, VMW(0));
            QKV_PHASE2(2, NOP_, NOP_);
        }
    }

    // ---- epilogue ----
#pragma unroll
    for (int nf = 0; nf < 6; ++nf) {
        int ncolg = col0 + wc * 96 + nf * 16 + li;
        float bv = bias[ncolg];
        int part = ncolg >> 10;
        int rem = ncolg & 1023;
        if (part < 2) {
            short* Dst = (part == 0) ? Qb : Kb;
#pragma unroll
            for (int mi = 0; mi < 4; ++mi) {
                int rbase = row0 + wr * 64 + mi * 16 + 4 * g;
#pragma unroll
                for (int j = 0; j < 4; ++j)
                    Dst[(size_t)(rbase + j) * E_ + rem] = f2bs(acc[mi][nf][j] + bv);
            }
        } else {
            int h = rem >> 6, d = rem & 63;
#pragma unroll
            for (int mi = 0; mi < 4; ++mi) {
                int s0 = row0 + wr * 64 + mi * 16 + 4 * g;
                int bb2 = s0 >> 11;
                int ss = s0 & 2047;
                uint2v p;
                p[0] = cvtpk(acc[mi][nf][0] + bv, acc[mi][nf][1] + bv);
                p[1] = cvtpk(acc[mi][nf][2] + bv, acc[mi][nf][3] + bv);
                *(uint2v*)&Vt[((size_t)(bb2 * H_ + h) * D_ + d) * S_ + ss] = p;
            }
        }
    }
}

// ================= 128x128 GEMM (out-proj), 2 merged phases/tile, 2 blocks/CU =================
#define OUT_MFMA1(Q, AF) \
    _Pragma("unroll") for (int nf = 0; nf < 4; ++nf) { \
        acc[(Q)][nf] = __builtin_amdgcn_mfma_f32_16x16x32_bf16(AF[0], bfrag[nf][0], acc[(Q)][nf], 0, 0, 0); \
        acc[(Q)][nf] = __builtin_amdgcn_mfma_f32_16x16x32_bf16(AF[1], bfrag[nf][1], acc[(Q)][nf], 0, 0, 0); \
    }

#define OUT_PHASE2(QA, STAGE_STMT, WAITV) do { \
    bf16x8 afA[2], afB[2]; \
    const char* lA0 = lA + (QA) * 4096; \
    const char* lA1 = lA + ((QA) + 1) * 4096; \
    _Pragma("unroll") for (int ks = 0; ks < 2; ++ks) { \
        afA[ks] = *(const bf16x8*)(lA0 + li * 128 + ((ks * 64 + g * 16) ^ ((li & 7) << 4))); \
        afB[ks] = *(const bf16x8*)(lA1 + li * 128 + ((ks * 64 + g * 16) ^ ((li & 7) << 4))); \
    } \
    STAGE_STMT; \
    __builtin_amdgcn_s_barrier(); \
    asm volatile("s_waitcnt lgkmcnt(0)" ::: "memory"); \
    __builtin_amdgcn_sched_barrier(0); \
    __builtin_amdgcn_s_setprio(1); \
    OUT_MFMA1(QA, afA); \
    OUT_MFMA1((QA) + 1, afB); \
    __builtin_amdgcn_s_setprio(0); \
    WAITV; \
    __builtin_amdgcn_s_barrier(); \
} while (0)

__global__ __launch_bounds__(256, 2) void gemm_out(
    const short* __restrict__ A, const short* __restrict__ Bt,
    const float* __restrict__ bias, float* __restrict__ Cf) {
    __shared__ __attribute__((aligned(16))) short ldsA[2][8192];  // [buf][4 calls][2 wr][16r][64k]
    __shared__ __attribute__((aligned(16))) short ldsB[2][8192];  // [buf][128r][64k]
    const int tid = threadIdx.x;
    const int lane = tid & 63;
    const int wid = tid >> 6;
    const int li = lane & 15, g = lane >> 4;
    const int wr = wid >> 1, wc = wid & 1;
    const int Kdim = E_;
    const int NT = Kdim >> 6;  // 16

    const int id = blockIdx.x;
    const int swz = (id & 7) * 64 + (id >> 3);
    const int bx = swz & 7, by = swz >> 3;
    const int row0 = by * 128, col0 = bx * 128;

    const int lr8 = lane >> 3;
    const int cstage = (((lane & 7) ^ (lr8 & 7)) << 4);

    auto stageA = [&](int buf, int kt) {
#pragma unroll
        for (int Q = 0; Q < 4; ++Q) {
            int grow = (wid >> 1) * 64 + Q * 16 + (wid & 1) * 8 + lr8;
            const char* src = (const char*)A +
                ((size_t)(row0 + grow) * Kdim + kt * 64) * 2 + cstage;
            char* dst = (char*)&ldsA[buf][0] + Q * 4096 + wid * 1024;
            __builtin_amdgcn_global_load_lds(gas(src), las(dst), 16, 0, 0);
        }
    };
    auto stageB = [&](int buf, int kt) {
#pragma unroll
        for (int i = 0; i < 4; ++i) {
            int grow = i * 32 + wid * 8 + lr8;
            const char* src = (const char*)Bt +
                ((size_t)(col0 + grow) * Kdim + kt * 64) * 2 + cstage;
            char* dst = (char*)&ldsB[buf][0] + i * 4096 + wid * 1024;
            __builtin_amdgcn_global_load_lds(gas(src), las(dst), 16, 0, 0);
        }
    };

    f32x4 acc[4][4];
#pragma unroll
    for (int m = 0; m < 4; ++m)
#pragma unroll
        for (int n = 0; n < 4; ++n) acc[m][n] = (f32x4){0.f, 0.f, 0.f, 0.f};

    stageB(0, 0);
    stageA(0, 0);
    asm volatile("s_waitcnt vmcnt(0)" ::: "memory");
    __syncthreads();

    for (int t = 0; t < NT; ++t) {
        const int cur = t & 1;
        const int nb = cur ^ 1;
        const int tn = t + 1;
        const bool st = (tn < NT);
        const char* lA = (const char*)&ldsA[cur][0] + wr * 2048;
        const char* lB = (const char*)&ldsB[cur][0];

        bf16x8 bfrag[4][2];
#pragma unroll
        for (int nf = 0; nf < 4; ++nf)
#pragma unroll
            for (int ks = 0; ks < 2; ++ks) {
                int r = wc * 64 + nf * 16 + li;
                bfrag[nf][ks] = *(const bf16x8*)(lB + r * 128 + ((ks * 64 + g * 16) ^ ((r & 7) << 4)));
            }
        if (st) {
            OUT_PHASE2(0, stageB(nb, tn), VMW(4));
            OUT_PHASE2(2, stageA(nb, tn), VMW(2));
        } else {
            OUT_PHASE2(0, NOP_, VMW(0));
            OUT_PHASE2(2, NOP_, NOP_);
        }
    }

    // ---- epilogue: fp32 + bias ----
#pragma unroll
    for (int nf = 0; nf < 4; ++nf) {
        int ncol = col0 + wc * 64 + nf * 16 + li;
        float bv = bias[ncol];
#pragma unroll
        for (int mi = 0; mi < 4; ++mi) {
            int rbase = row0 + wr * 64 + mi * 16 + 4 * g;
#pragma unroll
            for (int j = 0; j < 4; ++j)
                Cf[(size_t)(rbase + j) * E_ + ncol] = acc[mi][nf][j] + bv;
        }
    }
}

// ---------------- causal flash attention v9 (R15/R16 verified) ----------------
#define GRP 1040
__global__ __launch_bounds__(256, 4) void attn_kernel(
    const short* __restrict__ Qb, const short* __restrict__ Kb,
    const short* __restrict__ Vt, short* __restrict__ Ob) {
    __shared__ __attribute__((aligned(16))) char Kl[8 * GRP];
    __shared__ __attribute__((aligned(16))) char Vl[8 * GRP];
    const int lane = threadIdx.x & 63;
    const int wv = threadIdx.x >> 6;
    const int l31 = lane & 31;
    const int hi = lane >> 5;
    const int id = blockIdx.x;
    const int xcd = id & 7;
    const int r_ = id >> 3;
    const int qt = 15 - (r_ >> 3);
    const int bh = xcd * 8 + (r_ & 7);
    const int bb = bh >> 4, hh = bh & 15;
    const short* Qh = Qb + (size_t)bb * (S_ * E_) + hh * 64;
    const short* Kh = Kb + (size_t)bb * (S_ * E_) + hh * 64;
    const short* Vh = Vt + (size_t)bh * (D_ * S_);
    const float CEXP = 0.18033688011112042f;

    const int rstage = wv * 8 + (lane >> 3);
    const int cstage = (((lane & 7) ^ ((lane >> 3) & 7)) << 4);

    const int q0w = qt * 128 + wv * 32;
    const int q = q0w + l31;

    bf16x8 qf[4];
#pragma unroll
    for (int c = 0; c < 4; ++c)
        qf[c] = *(const bf16x8*)&Qh[(size_t)q * E_ + c * 16 + hi * 8];

    f32x16 acc[2];
#pragma unroll
    for (int d = 0; d < 2; ++d)
#pragma unroll
        for (int r = 0; r < 16; ++r) acc[d][r] = 0.f;
    float m = -3e38f, mC = 0.f, l = 0.f;

    const int nw = (q0w + 95) >> 6;
    const int nt = (qt * 128 + 191) >> 6;

    const int kg0 = (l31 >> 3) * GRP + (l31 & 7) * 128;
    const int kg1 = ((32 + l31) >> 3) * GRP + (l31 & 7) * 128;
    const int ksw = (l31 & 7) << 4;

    for (int it = 0; it < nt; ++it) {
        const int kt0 = it * 64;
#pragma unroll
        for (int half = 0; half < 2; ++half) {
            const int grp = half * 4 + wv;
            const char* gk = (const char*)(Kh + (size_t)(kt0 + half * 32 + rstage) * E_) + cstage;
            __builtin_amdgcn_global_load_lds(gas(gk), las(Kl + grp * GRP), 16, 0, 0);
            const char* gv = (const char*)Vh + (size_t)(half * 32 + rstage) * (S_ * 2) + (size_t)kt0 * 2 + cstage;
            __builtin_amdgcn_global_load_lds(gas(gv), las(Vl + grp * GRP), 16, 0, 0);
        }
        __syncthreads();
        if (it < nw) {
            f32x16 sc0, sc1;
#pragma unroll
            for (int r = 0; r < 16; ++r) { sc0[r] = 0.f; sc1[r] = 0.f; }
#pragma unroll
            for (int c = 0; c < 4; ++c) {
                bf16x8 kf0 = *(const bf16x8*)(Kl + kg0 + ((c * 32 + hi * 16) ^ ksw));
                bf16x8 kf1 = *(const bf16x8*)(Kl + kg1 + ((c * 32 + hi * 16) ^ ksw));
                sc0 = __builtin_amdgcn_mfma_f32_32x32x16_bf16(kf0, qf[c], sc0, 0, 0, 0);
                sc1 = __builtin_amdgcn_mfma_f32_32x32x16_bf16(kf1, qf[c], sc1, 0, 0, 0);
            }
            if (kt0 + 63 > q0w) {
                const int kb = kt0 + 4 * hi;
#pragma unroll
                for (int r = 0; r < 16; ++r) {
                    int key = kb + (r & 3) + 8 * (r >> 2);
                    sc0[r] = (key > q) ? -3e38f : sc0[r];
                    sc1[r] = (key + 32 > q) ? -3e38f : sc1[r];
                }
            }
            float tmx[8];
#pragma unroll
            for (int r = 0; r < 8; ++r)
                tmx[r] = fmaxf(fmaxf(sc0[2 * r], sc0[2 * r + 1]),
                               fmaxf(sc1[2 * r], sc1[2 * r + 1]));
            float tm = fmaxf(fmaxf(fmaxf(tmx[0], tmx[1]), fmaxf(tmx[2], tmx[3])),
                             fmaxf(fmaxf(tmx[4], tmx[5]), fmaxf(tmx[6], tmx[7])));
            tm = fmaxf(tm, __shfl_xor(tm, 32, 64));
            bool need = (tm > m + 16.0f);
            if (__ballot((int)need) != 0ull) {
                float mn = fmaxf(m, tm);
                float sf = exp2a((m - mn) * CEXP);
                m = mn; mC = mn * CEXP;
                l *= sf;
#pragma unroll
                for (int d = 0; d < 2; ++d)
#pragma unroll
                    for (int r = 0; r < 16; ++r) acc[d][r] *= sf;
            }
#pragma unroll
            for (int r = 0; r < 16; ++r) {
                sc0[r] = exp2a(fmaf(sc0[r], CEXP, -mC));
                sc1[r] = exp2a(fmaf(sc1[r], CEXP, -mC));
            }
            float s0 = 0.f, s1 = 0.f;
#pragma unroll
            for (int r = 0; r < 8; ++r) {
                s0 += sc0[2 * r] + sc0[2 * r + 1];
                s1 += sc1[2 * r] + sc1[2 * r + 1];
            }
            float ls = s0 + s1;
            ls += __shfl_xor(ls, 32, 64);
            l += ls;
            bf16x8 pf[4];
#pragma unroll
            for (int s = 0; s < 2; ++s) {
                const f32x16& p = s ? sc1 : sc0;
                unsigned a0 = cvtpk(p[0], p[1]),   a1 = cvtpk(p[2], p[3]);
                unsigned b0 = cvtpk(p[4], p[5]),   b1 = cvtpk(p[6], p[7]);
                unsigned a2 = cvtpk(p[8], p[9]),   a3 = cvtpk(p[10], p[11]);
                unsigned b2 = cvtpk(p[12], p[13]), b3 = cvtpk(p[14], p[15]);
                asm volatile("v_permlane32_swap_b32 %0, %1" : "+v"(a0), "+v"(b0));
                asm volatile("v_permlane32_swap_b32 %0, %1" : "+v"(a1), "+v"(b1));
                asm volatile("v_permlane32_swap_b32 %0, %1" : "+v"(a2), "+v"(b2));
                asm volatile("v_permlane32_swap_b32 %0, %1" : "+v"(a3), "+v"(b3));
                uint4v u1, u2;
                u1[0] = a0; u1[1] = a1; u1[2] = b0; u1[3] = b1;
                u2[0] = a2; u2[1] = a3; u2[2] = b2; u2[3] = b3;
                pf[s * 2] = __builtin_bit_cast(bf16x8, u1);
                pf[s * 2 + 1] = __builtin_bit_cast(bf16x8, u2);
            }
#pragma unroll
            for (int db = 0; db < 2; ++db) {
                const int row = db * 32 + l31;
                const int rsw = (row & 7) << 4;
                const char* vrow = Vl + (row >> 3) * GRP + (row & 7) * 128;
                bf16x8 v0 = *(const bf16x8*)(vrow + ((hi * 16) ^ rsw));
                bf16x8 v1 = *(const bf16x8*)(vrow + ((32 + hi * 16) ^ rsw));
                bf16x8 v2 = *(const bf16x8*)(vrow + ((64 + hi * 16) ^ rsw));
                bf16x8 v3 = *(const bf16x8*)(vrow + ((96 + hi * 16) ^ rsw));
                acc[db] = __builtin_amdgcn_mfma_f32_32x32x16_bf16(v0, pf[0], acc[db], 0, 0, 0);
                acc[db] = __builtin_amdgcn_mfma_f32_32x32x16_bf16(v1, pf[1], acc[db], 0, 0, 0);
                acc[db] = __builtin_amdgcn_mfma_f32_32x32x16_bf16(v2, pf[2], acc[db], 0, 0, 0);
                acc[db] = __builtin_amdgcn_mfma_f32_32x32x16_bf16(v3, pf[3], acc[db], 0, 0, 0);
            }
        }
        __syncthreads();
    }

    float rl = __builtin_amdgcn_rcpf(l);
    short* orow = Ob + ((size_t)(bb * S_ + q)) * E_ + hh * 64;
#pragma unroll
    for (int db = 0; db < 2; ++db)
#pragma unroll
        for (int rb = 0; rb < 4; ++rb) {
            uint2v pk;
            pk[0] = cvtpk(acc[db][rb * 4 + 0] * rl, acc[db][rb * 4 + 1] * rl);
            pk[1] = cvtpk(acc[db][rb * 4 + 2] * rl, acc[db][rb * 4 + 3] * rl);
            *(uint2v*)&orow[db * 32 + rb * 8 + hi * 4] = pk;
        }
}

extern "C" void kernel_launch(void* const* d_in, const int* in_sizes, int n_in,
                              void* d_out, int out_size, void* d_ws, size_t ws_size,
                              hipStream_t stream) {
    const float* x      = (const float*)d_in[0];
    const float* w_attn = (const float*)d_in[1];
    const float* b_attn = (const float*)d_in[2];
    const float* w_out  = (const float*)d_in[3];
    const float* b_out  = (const float*)d_in[4];
    float* out = (float*)d_out;

    char* ws = (char*)d_ws;
    short* Xbf  = (short*)(ws);                       // 16 MB (reused as attn output)
    short* Wat  = (short*)(ws + (16ull << 20));       // 6 MB  [3072][1024]
    short* Wot  = (short*)(ws + (22ull << 20));       // 2 MB  [1024][1024]
    short* Qb   = (short*)(ws + (24ull << 20));       // 16 MB flat [8192][1024]
    short* Kb   = (short*)(ws + (40ull << 20));       // 16 MB flat [8192][1024]
    short* Vt   = (short*)(ws + (56ull << 20));       // 16 MB [B,H,D,S]
    short* Obuf = Xbf;

    prologue<<<6144, 256, 0, stream>>>(x, Xbf, w_attn, Wat, w_out, Wot);

    gemm_qkv<<<1024, 256, 0, stream>>>(Xbf, Wat, b_attn, Qb, Kb, Vt);

    attn_kernel<<<1024, 256, 0, stream>>>(Qb, Kb, Vt, Obuf);

    gemm_out<<<512, 256, 0, stream>>>(Obuf, Wot, b_out, out);
}